// Round 7
// baseline (7267.841 us; speedup 1.0000x reference)
//
#include <hip/hip_runtime.h>

// ---------------------------------------------------------------------------
// RecurrentNet scan:
//   h' = tanh(U1_t + h@W1h + sigmoid(c@W1g)*h)
//   c' = sigmoid(U2_t + c@W2h) * tanh(h@W2g)
// U1/U2 hoisted.  16 persistent WGs on XCD 0; state via plain L2 (16-slot
// rotation).  ROUND 7: decentralized barrier -- per-stream per-WG per-LINE
// flags; every wave polls its own flag set with predicated lane-parallel
// RMWs (fetch_add 0x10000, non-elidable); producers post +1 after their own
// vmcnt drain.  Only ONE __syncthreads per step (xg/xt LDS handoff).
// Fallback (WGs not co-resident): round-2-proven MALL semantics.
// ---------------------------------------------------------------------------

typedef unsigned short u16;
typedef unsigned int   u32;
typedef __attribute__((ext_vector_type(8))) short s8v;   // 8 x bf16 (4 VGPR)
typedef __attribute__((ext_vector_type(4))) float f4v;

__device__ __forceinline__ u16 f2bf_rne(float f){
  u32 u = __float_as_uint(f);
  u32 r = u + 0x7fffu + ((u >> 16) & 1u);
  return (u16)(r >> 16);
}
__device__ __forceinline__ float bf2f(u16 h){ return __uint_as_float(((u32)h) << 16); }
__device__ __forceinline__ f4v MFMA(s8v a, s8v b, f4v c){
  return __builtin_amdgcn_mfma_f32_16x16x32_bf16(a, b, c, 0, 0, 0);
}
__device__ __forceinline__ float sigmoidf_(float x){ return 1.0f / (1.0f + __expf(-x)); }
__device__ __forceinline__ float tanh_fast(float x){
  float e = __expf(2.0f * x);           // inf->1, 0->-1 at the extremes
  return 1.0f - 2.0f / (e + 1.0f);
}

// CC=true: sc0 sc1 (MALL-coherent, round-2-proven). CC=false: plain (XCD-L2).
template<bool CC> __device__ __forceinline__ s8v ld16(const u16* p){
  s8v r;
  if (CC) asm volatile("global_load_dwordx4 %0, %1, off sc0 sc1" : "=v"(r) : "v"(p));
  else    asm volatile("global_load_dwordx4 %0, %1, off"         : "=v"(r) : "v"(p));
  return r;
}
template<bool CC> __device__ __forceinline__ void st2(u16* p, u32 v){
  if (CC) asm volatile("global_store_short %0, %1, off sc0 sc1" :: "v"(p), "v"(v) : "memory");
  else    asm volatile("global_store_short %0, %1, off"         :: "v"(p), "v"(v) : "memory");
}
__device__ __forceinline__ void store_dword_cc(u32* p, u32 v){
  asm volatile("global_store_dword %0, %1, off sc0 sc1" :: "v"(p), "v"(v) : "memory");
}
__device__ __forceinline__ void store_dword_plain_wait(u32* p, u32 v){
  asm volatile("global_store_dword %0, %1, off\n\ts_waitcnt vmcnt(0)"
               :: "v"(p), "v"(v) : "memory");
}
__device__ __forceinline__ u32 load_dword_plain_wait(const u32* p){
  u32 r;
  asm volatile("global_load_dword %0, %1, off\n\ts_waitcnt vmcnt(0)"
               : "=v"(r) : "v"(p));
  return r;
}

#define SEQT 1024
#define NWG  16
#define PROT 16                          // state rotation slots

// ws layout (bytes)
static const size_t OFF_U1  = 0;                      // f32 [1024][16][512]  32MB
static const size_t OFF_U2  = 33554432;               // bf16 [1024][16][512] 16MB
static const size_t OFF_WCT = OFF_U2 + 16777216;      // bf16 [1024][512] 1MB (dead after gemmk)
static const size_t OFF_ST  = OFF_WCT;                // ALIAS: u16 [16 slots][4][16][512] 1MB
static const size_t OFF_WT  = OFF_WCT + 1048576;      // bf16 [4][512][512] 2MB
static const size_t OFF_BC  = OFF_WT + 2097152;       // f32 [1024] (4KB)
static const size_t OFF_FL  = OFF_BC + 4096;          // u32 [1024][16] 64KB (CC mode)
static const size_t OFF_TOK = OFF_FL + 65536;         // u32 [16][16] tokens 4KB
static const size_t OFF_PRS = OFF_TOK + 4096;         // u32 [16][16] present 4KB
static const size_t OFF_CTL = OFF_PRS + 4096;         // u32 cnt@0, mode@16  4KB
static const size_t OFF_CN  = OFF_CTL + 4096;         // u32 [1024] (CC mode, unused fast)
static const size_t OFF_HF2 = OFF_CN + 4096;          // u32 [1024][16][16] h-flags 1MB
static const size_t OFF_CF2 = OFF_HF2 + 1048576;      // u32 [1024][16][16] c-flags 1MB

// --- Wcombt[n_g][i] = sum_k Wfc[i][k] * (Wx[k][n] + Wx[k+512][n]), bf16 ---
__global__ void wcombk(const float* __restrict__ Wfc, const float* __restrict__ W1x,
                       const float* __restrict__ W2x, u16* __restrict__ Wct){
  __shared__ float A[16][17], B[16][17];
  const float* Wx = blockIdx.z ? W2x : W1x;
  int i0 = blockIdx.y * 16, n0 = blockIdx.x * 16;
  int tx = threadIdx.x, ty = threadIdx.y;
  float acc = 0.f;
  for (int kc = 0; kc < 512; kc += 16){
    A[ty][tx] = Wfc[(size_t)(i0 + ty) * 512 + kc + tx];
    B[ty][tx] = Wx[(size_t)(kc + ty) * 512 + n0 + tx]
              + Wx[(size_t)(kc + ty + 512) * 512 + n0 + tx];
    __syncthreads();
    #pragma unroll
    for (int kk = 0; kk < 16; ++kk) acc += A[ty][kk] * B[kk][tx];
    __syncthreads();
  }
  Wct[(size_t)(blockIdx.z * 512 + n0 + tx) * 512 + i0 + ty] = f2bf_rne(acc);
}

// --- bc[n_g] = sum_k bfc[k]*(Wx[k][n]+Wx[k+512][n]), f32 ---
__global__ void bcombk(const float* __restrict__ bfc, const float* __restrict__ W1x,
                       const float* __restrict__ W2x, float* __restrict__ bc){
  int n = blockIdx.x * 256 + threadIdx.x;            // 0..1023
  const float* Wx = (n < 512) ? W1x : W2x;
  int nl = n & 511;
  float acc = 0.f;
  for (int k = 0; k < 512; ++k)
    acc += bfc[k] * (Wx[(size_t)k * 512 + nl] + Wx[(size_t)(k + 512) * 512 + nl]);
  bc[n] = acc;
}

// --- Wt[m][n][k] = bf16(Wm[k][n]) for m in {W1h,W1g,W2h,W2g} ---
__global__ void wtk(const float* __restrict__ A, const float* __restrict__ B,
                    const float* __restrict__ C, const float* __restrict__ D,
                    u16* __restrict__ Wt){
  __shared__ float tile[32][33];
  const float* src = (blockIdx.z == 0) ? A : (blockIdx.z == 1) ? B
                    : (blockIdx.z == 2) ? C : D;
  int n0 = blockIdx.x * 32, k0 = blockIdx.y * 32;
  for (int i = threadIdx.y; i < 32; i += 8)
    tile[i][threadIdx.x] = src[(size_t)(k0 + i) * 512 + n0 + threadIdx.x];
  __syncthreads();
  for (int i = threadIdx.y; i < 32; i += 8)
    Wt[(size_t)blockIdx.z * 262144 + (size_t)(n0 + i) * 512 + k0 + threadIdx.x]
        = f2bf_rne(tile[threadIdx.x][i]);
}

// --- U GEMM: [16384,512] x [512,1024] ; A = x split to bf16 hi+lo (2 passes) ---
__global__ __launch_bounds__(256) void gemmk(
    const float* __restrict__ x, const u16* __restrict__ Wct,
    const float* __restrict__ bc, float* __restrict__ U1, u16* __restrict__ U2){
  int l = threadIdx.x & 63, w = threadIdx.x >> 6;
  int lr = l & 15, lk = l >> 4;
  int m0 = blockIdx.y * 128 + (w & 1) * 64;
  int n0 = blockIdx.x * 64 + (w >> 1) * 32;
  f4v acc[4][2] = {};
  for (int ks = 0; ks < 16; ++ks){
    int k0 = ks * 32 + lk * 8;
    s8v bh0 = *(const s8v*)(Wct + (size_t)(n0 + lr) * 512 + k0);
    s8v bh1 = *(const s8v*)(Wct + (size_t)(n0 + 16 + lr) * 512 + k0);
    #pragma unroll
    for (int mi = 0; mi < 4; ++mi){
      const float* xp = x + (size_t)(m0 + mi * 16 + lr) * 512 + k0;
      f4v v0 = *(const f4v*)xp;
      f4v v1 = *(const f4v*)(xp + 4);
      s8v ah, al;
      #pragma unroll
      for (int j = 0; j < 4; ++j){
        { u32 u = __float_as_uint(v0[j]); ah[j] = (short)(u >> 16);
          float lof = v0[j] - __uint_as_float(u & 0xffff0000u);
          al[j] = (short)(__float_as_uint(lof) >> 16); }
        { u32 u = __float_as_uint(v1[j]); ah[j + 4] = (short)(u >> 16);
          float lof = v1[j] - __uint_as_float(u & 0xffff0000u);
          al[j + 4] = (short)(__float_as_uint(lof) >> 16); }
      }
      acc[mi][0] = MFMA(ah, bh0, acc[mi][0]);
      acc[mi][0] = MFMA(al, bh0, acc[mi][0]);
      acc[mi][1] = MFMA(ah, bh1, acc[mi][1]);
      acc[mi][1] = MFMA(al, bh1, acc[mi][1]);
    }
  }
  #pragma unroll
  for (int mi = 0; mi < 4; ++mi)
    #pragma unroll
    for (int ni = 0; ni < 2; ++ni){
      int n = n0 + ni * 16 + lr;
      float badd = bc[n];
      #pragma unroll
      for (int j = 0; j < 4; ++j){
        int r = m0 + mi * 16 + lk * 4 + j;        // C/D: row=(l>>4)*4+j, col=l&15
        int b = r >> 10, t = r & 1023;
        size_t oi = (size_t)(t * 16 + b) * 512;
        float v = acc[mi][ni][j] + badd;
        if (n < 512) U1[oi + n] = v;
        else         U2[oi + n - 512] = f2bf_rne(v);
      }
    }
}

// --- FAST scan: decentralized per-stream flag barrier, 1 syncthreads/step ---
__device__ __forceinline__ void scan_fast(
    int wg, int tid,
    const float* __restrict__ U1, const u16* __restrict__ U2,
    const u16* __restrict__ Wt, u16* __restrict__ st,
    u32* __restrict__ hfl, u32* __restrict__ cfl,
    float* __restrict__ out, float* xg, float* xt){
  const int w = tid >> 6, l = tid & 63;      // wave 0:W1h 1:W1g 2:W2h 3:W2g
  const int lr = l & 15, lk = l >> 4;
  const int ncol0 = wg * 32 + lr;

  s8v bf0[16], bf1[16];
  {
    const u16* Wm = Wt + (size_t)w * (512 * 512);
    #pragma unroll
    for (int ks = 0; ks < 16; ++ks){
      bf0[ks] = *(const s8v*)(Wm + (size_t)ncol0 * 512 + ks * 32 + lk * 8);
      bf1[ks] = *(const s8v*)(Wm + (size_t)(ncol0 + 16) * 512 + ks * 32 + lk * 8);
    }
  }
  const bool useH = (w == 0) || (w == 3);
  u32* myfl = useH ? hfl : cfl;              // flag set this wave CONSUMES
  float hp0[4] = {0, 0, 0, 0}, hp1[4] = {0, 0, 0, 0};

  // U register double-buffer
  float un0[4], un1[4], uc0[4], uc1[4];
  u32   ur0[4], ur1[4];
  if (w == 0){
    #pragma unroll
    for (int j = 0; j < 4; ++j){
      size_t ro = (size_t)(lk * 4 + j) * 512;
      un0[j] = U1[ro + ncol0];
      un1[j] = U1[ro + ncol0 + 16];
    }
  } else if (w == 2){
    #pragma unroll
    for (int j = 0; j < 4; ++j){
      size_t ro = (size_t)(lk * 4 + j) * 512;
      ur0[j] = U2[ro + ncol0];
      ur1[j] = U2[ro + ncol0 + 16];
    }
  }

  for (int t = 0; t < SEQT; ++t){
    if (t > 0){
      // every wave polls its own stream's 16 per-WG flag lines; lanes stop
      // RMWing once their line is seen (predicated); high-half adds wrap
      // mod 2^32 and never touch the low 16-bit post count.
      u32* fl = myfl + (size_t)(t - 1) * (NWG * 16);
      u32 seen = (l < NWG) ? 0u : 1u;
      int g2 = 0;
      for (;;){
        if (!seen){
          u32 v = __hip_atomic_fetch_add(fl + l * 16, 0x10000u,
                                         __ATOMIC_RELAXED, __HIP_MEMORY_SCOPE_WORKGROUP);
          if ((v & 0xffffu) != 0u) seen = 1u;
        }
        if (__all(seen != 0u)) break;
        if (++g2 > 2000000) break;          // fails loudly, never silently
      }
      __builtin_amdgcn_sched_barrier(0);
    }
    // state read from rotation slot t%PROT (slot 0 pre-zeroed = initial state)
    u16* rb = st + (size_t)(t & (PROT - 1)) * 32768 + (useH ? 0 : 16384);
    s8v ah[16], al[16];
    {
      u16* bhp = rb + lr * 512 + lk * 8;
      u16* blp = rb + 8192 + lr * 512 + lk * 8;
      #pragma unroll
      for (int ks = 0; ks < 16; ++ks){
        ah[ks] = ld16<false>(bhp + ks * 32);
        al[ks] = ld16<false>(blp + ks * 32);
      }
    }
    asm volatile("s_waitcnt vmcnt(0)" ::: "memory");   // also retires U loads
    __builtin_amdgcn_sched_barrier(0);

    if (w == 0){
      #pragma unroll
      for (int j = 0; j < 4; ++j){ uc0[j] = un0[j]; uc1[j] = un1[j]; }
    } else if (w == 2){
      #pragma unroll
      for (int j = 0; j < 4; ++j){
        uc0[j] = __uint_as_float(ur0[j] << 16);
        uc1[j] = __uint_as_float(ur1[j] << 16);
      }
    }

    f4v a0 = {0, 0, 0, 0}, a1 = {0, 0, 0, 0};
    f4v b0 = {0, 0, 0, 0}, b1 = {0, 0, 0, 0};
    #pragma unroll
    for (int ks = 0; ks < 16; ++ks){
      a0 = MFMA(ah[ks], bf0[ks], a0);
      a1 = MFMA(ah[ks], bf1[ks], a1);
      b0 = MFMA(al[ks], bf0[ks], b0);
      b1 = MFMA(al[ks], bf1[ks], b1);
    }
    #pragma unroll
    for (int j = 0; j < 4; ++j){ a0[j] += b0[j]; a1[j] += b1[j]; }

    const int par = t & 1;
    if (w == 1){
      #pragma unroll
      for (int j = 0; j < 4; ++j){
        xg[((par * 2 + 0) * 16 + lk * 4 + j) * 16 + lr] = sigmoidf_(a0[j]);
        xg[((par * 2 + 1) * 16 + lk * 4 + j) * 16 + lr] = sigmoidf_(a1[j]);
      }
    } else if (w == 3){
      #pragma unroll
      for (int j = 0; j < 4; ++j){
        xt[((par * 2 + 0) * 16 + lk * 4 + j) * 16 + lr] = tanh_fast(a0[j]);
        xt[((par * 2 + 1) * 16 + lk * 4 + j) * 16 + lr] = tanh_fast(a1[j]);
      }
    }
    __syncthreads();     // the ONLY barrier per step (xg/xt handoff)
    u16* wb = st + (size_t)((t + 1) & (PROT - 1)) * 32768;
    const int tn = (t + 1 < SEQT) ? t + 1 : t;
    if (w == 0){
      float hn0v[4], hn1v[4];
      #pragma unroll
      for (int j = 0; j < 4; ++j){
        int b = lk * 4 + j;
        float hn0 = tanh_fast(uc0[j] + a0[j] + xg[((par * 2 + 0) * 16 + b) * 16 + lr] * hp0[j]);
        float hn1 = tanh_fast(uc1[j] + a1[j] + xg[((par * 2 + 1) * 16 + b) * 16 + lr] * hp1[j]);
        hp0[j] = hn0; hp1[j] = hn1;
        hn0v[j] = hn0; hn1v[j] = hn1;
        u32 u0 = __float_as_uint(hn0), u1 = __float_as_uint(hn1);
        int bi = b * 512;
        st2<false>(wb + bi + ncol0,      u0 >> 16);
        st2<false>(wb + bi + ncol0 + 16, u1 >> 16);
        float lo0 = hn0 - __uint_as_float(u0 & 0xffff0000u);
        float lo1 = hn1 - __uint_as_float(u1 & 0xffff0000u);
        st2<false>(wb + 8192 + bi + ncol0,      __float_as_uint(lo0) >> 16);
        st2<false>(wb + 8192 + bi + ncol0 + 16, __float_as_uint(lo1) >> 16);
      }
      #pragma unroll
      for (int j = 0; j < 4; ++j){
        size_t ro = (size_t)(tn * 16 + lk * 4 + j) * 512;
        un0[j] = U1[ro + ncol0];
        un1[j] = U1[ro + ncol0 + 16];
      }
      asm volatile("s_waitcnt vmcnt(8)" ::: "memory");   // 16 state stores done
      if (l == 0)
        __hip_atomic_fetch_add(hfl + (size_t)t * (NWG * 16) + wg * 16, 1u,
                               __ATOMIC_RELAXED, __HIP_MEMORY_SCOPE_WORKGROUP);
      #pragma unroll
      for (int j = 0; j < 4; ++j){
        int b = lk * 4 + j;
        size_t ob = (size_t)b * (SEQT * 512) + (size_t)t * 512;
        out[ob + ncol0]      = hn0v[j];
        out[ob + ncol0 + 16] = hn1v[j];
        if (t == SEQT - 1){
          out[8388608 + (size_t)b * 512 + ncol0]      = hn0v[j];
          out[8388608 + (size_t)b * 512 + ncol0 + 16] = hn1v[j];
        }
      }
    } else if (w == 2){
      float cn0v[4], cn1v[4];
      #pragma unroll
      for (int j = 0; j < 4; ++j){
        int b = lk * 4 + j;
        float cn0 = sigmoidf_(uc0[j] + a0[j]) * xt[((par * 2 + 0) * 16 + b) * 16 + lr];
        float cn1 = sigmoidf_(uc1[j] + a1[j]) * xt[((par * 2 + 1) * 16 + b) * 16 + lr];
        cn0v[j] = cn0; cn1v[j] = cn1;
        u32 u0 = __float_as_uint(cn0), u1 = __float_as_uint(cn1);
        int bi = b * 512;
        st2<false>(wb + 16384 + bi + ncol0,      u0 >> 16);
        st2<false>(wb + 16384 + bi + ncol0 + 16, u1 >> 16);
        float lo0 = cn0 - __uint_as_float(u0 & 0xffff0000u);
        float lo1 = cn1 - __uint_as_float(u1 & 0xffff0000u);
        st2<false>(wb + 24576 + bi + ncol0,      __float_as_uint(lo0) >> 16);
        st2<false>(wb + 24576 + bi + ncol0 + 16, __float_as_uint(lo1) >> 16);
      }
      #pragma unroll
      for (int j = 0; j < 4; ++j){
        size_t ro = (size_t)(tn * 16 + lk * 4 + j) * 512;
        ur0[j] = U2[ro + ncol0];
        ur1[j] = U2[ro + ncol0 + 16];
      }
      asm volatile("s_waitcnt vmcnt(8)" ::: "memory");
      if (l == 0)
        __hip_atomic_fetch_add(cfl + (size_t)t * (NWG * 16) + wg * 16, 1u,
                               __ATOMIC_RELAXED, __HIP_MEMORY_SCOPE_WORKGROUP);
      if (t == SEQT - 1){
        #pragma unroll
        for (int j = 0; j < 4; ++j){
          int b = lk * 4 + j;
          out[8396800 + (size_t)b * 512 + ncol0]      = cn0v[j];
          out[8396800 + (size_t)b * 512 + ncol0 + 16] = cn1v[j];
        }
      }
    }
    // w1/w3: straight to next poll
  }
}

// --- CC fallback scan (round-2/6-proven MALL path), used for modes 2/3 ---
__device__ __forceinline__ void scan_cc(
    int wg, int tid,
    const float* __restrict__ U1, const u16* __restrict__ U2,
    const u16* __restrict__ Wt, u16* __restrict__ st,
    u32* __restrict__ flags, float* __restrict__ out, float* xg, float* xt){
  const int w = tid >> 6, l = tid & 63;
  const int lr = l & 15, lk = l >> 4;
  const int ncol0 = wg * 32 + lr;
  s8v bf0[16], bf1[16];
  {
    const u16* Wm = Wt + (size_t)w * (512 * 512);
    #pragma unroll
    for (int ks = 0; ks < 16; ++ks){
      bf0[ks] = *(const s8v*)(Wm + (size_t)ncol0 * 512 + ks * 32 + lk * 8);
      bf1[ks] = *(const s8v*)(Wm + (size_t)(ncol0 + 16) * 512 + ks * 32 + lk * 8);
    }
  }
  const bool useH = (w == 0) || (w == 3);
  float hp0[4] = {0, 0, 0, 0}, hp1[4] = {0, 0, 0, 0};
  long guard = 0;
  for (int t = 0; t < SEQT; ++t){
    float uu0[4], uu1[4];
    if (w == 0){
      #pragma unroll
      for (int j = 0; j < 4; ++j){
        size_t ro = (size_t)(t * 16 + lk * 4 + j) * 512;
        uu0[j] = U1[ro + ncol0];
        uu1[j] = U1[ro + ncol0 + 16];
      }
    } else if (w == 2){
      #pragma unroll
      for (int j = 0; j < 4; ++j){
        size_t ro = (size_t)(t * 16 + lk * 4 + j) * 512;
        uu0[j] = bf2f(U2[ro + ncol0]);
        uu1[j] = bf2f(U2[ro + ncol0 + 16]);
      }
    }
    if (t > 0){
      const u32* fl = flags + (size_t)(t - 1) * NWG;
      for (;;){
        u32 v = 1u;
        if (l < NWG) v = __hip_atomic_load(fl + l, __ATOMIC_RELAXED, __HIP_MEMORY_SCOPE_AGENT);
        if (__all(v != 0u)) break;
        if (++guard > 1000000L) break;
      }
      __builtin_amdgcn_sched_barrier(0);
    }
    u16* rb = st + (size_t)(t & (PROT - 1)) * 32768 + (useH ? 0 : 16384);
    s8v ah[16], al[16];
    {
      u16* bhp = rb + lr * 512 + lk * 8;
      u16* blp = rb + 8192 + lr * 512 + lk * 8;
      #pragma unroll
      for (int ks = 0; ks < 16; ++ks){
        ah[ks] = ld16<true>(bhp + ks * 32);
        al[ks] = ld16<true>(blp + ks * 32);
      }
    }
    asm volatile("s_waitcnt vmcnt(0)" ::: "memory");
    __builtin_amdgcn_sched_barrier(0);
    f4v a0 = {0, 0, 0, 0}, a1 = {0, 0, 0, 0};
    f4v b0 = {0, 0, 0, 0}, b1 = {0, 0, 0, 0};
    #pragma unroll
    for (int ks = 0; ks < 16; ++ks){
      a0 = MFMA(ah[ks], bf0[ks], a0);
      a1 = MFMA(ah[ks], bf1[ks], a1);
      b0 = MFMA(al[ks], bf0[ks], b0);
      b1 = MFMA(al[ks], bf1[ks], b1);
    }
    #pragma unroll
    for (int j = 0; j < 4; ++j){ a0[j] += b0[j]; a1[j] += b1[j]; }
    if (w == 1){
      #pragma unroll
      for (int j = 0; j < 4; ++j){
        xg[(0 * 16 + lk * 4 + j) * 16 + lr] = sigmoidf_(a0[j]);
        xg[(1 * 16 + lk * 4 + j) * 16 + lr] = sigmoidf_(a1[j]);
      }
    } else if (w == 3){
      #pragma unroll
      for (int j = 0; j < 4; ++j){
        xt[(0 * 16 + lk * 4 + j) * 16 + lr] = tanh_fast(a0[j]);
        xt[(1 * 16 + lk * 4 + j) * 16 + lr] = tanh_fast(a1[j]);
      }
    }
    __syncthreads();
    u16* wb = st + (size_t)((t + 1) & (PROT - 1)) * 32768;
    float hn0v[4], hn1v[4], cn0v[4], cn1v[4];
    if (w == 0){
      #pragma unroll
      for (int j = 0; j < 4; ++j){
        int b = lk * 4 + j;
        float hn0 = tanh_fast(uu0[j] + a0[j] + xg[(0 * 16 + b) * 16 + lr] * hp0[j]);
        float hn1 = tanh_fast(uu1[j] + a1[j] + xg[(1 * 16 + b) * 16 + lr] * hp1[j]);
        hp0[j] = hn0; hp1[j] = hn1;
        hn0v[j] = hn0; hn1v[j] = hn1;
        u32 u0 = __float_as_uint(hn0), u1 = __float_as_uint(hn1);
        int bi = b * 512;
        st2<true>(wb + bi + ncol0,      u0 >> 16);
        st2<true>(wb + bi + ncol0 + 16, u1 >> 16);
        float lo0 = hn0 - __uint_as_float(u0 & 0xffff0000u);
        float lo1 = hn1 - __uint_as_float(u1 & 0xffff0000u);
        st2<true>(wb + 8192 + bi + ncol0,      __float_as_uint(lo0) >> 16);
        st2<true>(wb + 8192 + bi + ncol0 + 16, __float_as_uint(lo1) >> 16);
      }
      asm volatile("s_waitcnt vmcnt(0)" ::: "memory");
    } else if (w == 2){
      #pragma unroll
      for (int j = 0; j < 4; ++j){
        int b = lk * 4 + j;
        float cn0 = sigmoidf_(uu0[j] + a0[j]) * xt[(0 * 16 + b) * 16 + lr];
        float cn1 = sigmoidf_(uu1[j] + a1[j]) * xt[(1 * 16 + b) * 16 + lr];
        cn0v[j] = cn0; cn1v[j] = cn1;
        u32 u0 = __float_as_uint(cn0), u1 = __float_as_uint(cn1);
        int bi = b * 512;
        st2<true>(wb + 16384 + bi + ncol0,      u0 >> 16);
        st2<true>(wb + 16384 + bi + ncol0 + 16, u1 >> 16);
        float lo0 = cn0 - __uint_as_float(u0 & 0xffff0000u);
        float lo1 = cn1 - __uint_as_float(u1 & 0xffff0000u);
        st2<true>(wb + 24576 + bi + ncol0,      __float_as_uint(lo0) >> 16);
        st2<true>(wb + 24576 + bi + ncol0 + 16, __float_as_uint(lo1) >> 16);
      }
      asm volatile("s_waitcnt vmcnt(0)" ::: "memory");
    }
    __syncthreads();
    if (tid == 0) store_dword_cc(flags + (size_t)t * NWG + wg, 1u);
    if (w == 0){
      #pragma unroll
      for (int j = 0; j < 4; ++j){
        int b = lk * 4 + j;
        size_t ob = (size_t)b * (SEQT * 512) + (size_t)t * 512;
        out[ob + ncol0]      = hn0v[j];
        out[ob + ncol0 + 16] = hn1v[j];
        if (t == SEQT - 1){
          out[8388608 + (size_t)b * 512 + ncol0]      = hn0v[j];
          out[8388608 + (size_t)b * 512 + ncol0 + 16] = hn1v[j];
        }
      }
    } else if (w == 2 && t == SEQT - 1){
      #pragma unroll
      for (int j = 0; j < 4; ++j){
        int b = lk * 4 + j;
        out[8396800 + (size_t)b * 512 + ncol0]      = cn0v[j];
        out[8396800 + (size_t)b * 512 + ncol0 + 16] = cn1v[j];
      }
    }
  }
}

// --- persistent scan: election onto XCD0 + coherence probe + fallback ---
__global__ __launch_bounds__(256, 1) void recurk(
    const float* __restrict__ U1, const u16* __restrict__ U2,
    const u16* __restrict__ Wt, u16* __restrict__ st,
    u32* __restrict__ flags, u32* __restrict__ hfl, u32* __restrict__ cfl,
    u32* __restrict__ tok, u32* __restrict__ prs,
    u32* __restrict__ ctl, float* __restrict__ out){
  const int tid = threadIdx.x;
  __shared__ int slot_sh, mode_sh;
  __shared__ float xg[4 * 16 * 16], xt[4 * 16 * 16];
  u32* cntp  = ctl;
  u32* modep = ctl + 16;

  if (tid == 0){
    int s = -1;
    u32 xcc;
    asm volatile("s_getreg_b32 %0, hwreg(HW_REG_XCC_ID)" : "=s"(xcc));
    if ((xcc & 0xfu) == 0u)
      s = (int)__hip_atomic_fetch_add(cntp, 1u, __ATOMIC_RELAXED,
                                      __HIP_MEMORY_SCOPE_AGENT);
    slot_sh = s;
  }
  __syncthreads();
  const int slot = slot_sh;

  if (tid == 0){
    if (slot >= 0 && slot < NWG){
      store_dword_plain_wait(tok + slot * 16, 0x5A5A0000u + (u32)slot);
      __hip_atomic_store(prs + slot * 16, 1u, __ATOMIC_RELAXED,
                         __HIP_MEMORY_SCOPE_AGENT);
    }
    if (blockIdx.x == 0){
      long g = 0;
      for (;;){
        u32 c = __hip_atomic_load(cntp, __ATOMIC_RELAXED, __HIP_MEMORY_SCOPE_AGENT);
        if (c >= NWG) break;
        if (++g > 2000000L){ atomicCAS(modep, 0u, 2u); break; }
      }
    }
    if (slot == 0){
      bool ok = true;
      long g = 0;
      for (int s2 = 1; s2 < NWG && ok; ++s2){
        for (;;){
          u32 p = __hip_atomic_load(prs + s2 * 16, __ATOMIC_RELAXED,
                                    __HIP_MEMORY_SCOPE_AGENT);
          if (p) break;
          if (++g > 5000000L){ ok = false; break; }
        }
      }
      if (ok){
        for (int s2 = 1; s2 < NWG; ++s2){
          u32 v = load_dword_plain_wait(tok + s2 * 16);
          if (v != 0x5A5A0000u + (u32)s2){ ok = false; break; }
        }
      }
      atomicCAS(modep, 0u, ok ? 1u : 3u);
    }
    long g = 0;
    u32 m;
    for (;;){
      m = __hip_atomic_load(modep, __ATOMIC_RELAXED, __HIP_MEMORY_SCOPE_AGENT);
      if (m) break;
      if (++g > 50000000L){ m = 3u; break; }
    }
    mode_sh = (int)m;
  }
  __syncthreads();
  const int mode = mode_sh;

  int wg; bool part;
  if (mode == 2){ wg = blockIdx.x; part = (wg < NWG); }
  else          { wg = slot;       part = (slot >= 0 && slot < NWG); }
  if (!part) return;

  if (mode == 1) scan_fast(wg, tid, U1, U2, Wt, st, hfl, cfl, out, xg, xt);
  else           scan_cc (wg, tid, U1, U2, Wt, st, flags, out, xg, xt);
}

extern "C" void kernel_launch(void* const* d_in, const int* in_sizes, int n_in,
                              void* d_out, int out_size, void* d_ws, size_t ws_size,
                              hipStream_t stream){
  const float* x   = (const float*)d_in[0];
  const float* Wfc = (const float*)d_in[1];
  const float* bfc = (const float*)d_in[2];
  const float* W1x = (const float*)d_in[3];
  const float* W1h = (const float*)d_in[4];
  const float* W1g = (const float*)d_in[5];
  const float* W2x = (const float*)d_in[6];
  const float* W2h = (const float*)d_in[7];
  const float* W2g = (const float*)d_in[8];

  char* ws = (char*)d_ws;
  float* U1   = (float*)(ws + OFF_U1);
  u16*   U2   = (u16*)  (ws + OFF_U2);
  u16*   Wct  = (u16*)  (ws + OFF_WCT);
  u16*   st   = (u16*)  (ws + OFF_ST);     // aliases Wct (dead after gemmk)
  u16*   Wt   = (u16*)  (ws + OFF_WT);
  float* bc   = (float*)(ws + OFF_BC);
  u32*   flags= (u32*)  (ws + OFF_FL);
  u32*   tok  = (u32*)  (ws + OFF_TOK);
  u32*   prs  = (u32*)  (ws + OFF_PRS);
  u32*   ctl  = (u32*)  (ws + OFF_CTL);
  u32*   hfl  = (u32*)  (ws + OFF_HF2);
  u32*   cfl  = (u32*)  (ws + OFF_CF2);
  float* out  = (float*)d_out;

  // zero flags + tokens + present + control (+CC counters) every launch
  hipMemsetAsync(ws + OFF_FL, 0, 65536 + 4096 + 4096 + 4096 + 4096, stream);
  // zero the decentralized flag arrays (2 MB)
  hipMemsetAsync(ws + OFF_HF2, 0, 2097152, stream);

  wcombk<<<dim3(32, 32, 2), dim3(16, 16), 0, stream>>>(Wfc, W1x, W2x, Wct);
  bcombk<<<dim3(4), dim3(256), 0, stream>>>(bfc, W1x, W2x, bc);
  wtk   <<<dim3(16, 16, 4), dim3(32, 8), 0, stream>>>(W1h, W1g, W2h, W2g, Wt);
  gemmk <<<dim3(16, 128), dim3(256), 0, stream>>>(x, Wct, bc, U1, U2);
  // Wct is dead now; zero the aliased state-rotation region (slot 0 = h0,c0)
  hipMemsetAsync(ws + OFF_ST, 0, 1048576, stream);
  recurk<<<dim3(256), dim3(256), 0, stream>>>(U1, U2, Wt, st, flags, hfl, cfl, tok, prs, ctl, out);
}

// Round 8
// 6237.309 us; speedup vs baseline: 1.1652x; 1.1652x over previous
//
#include <hip/hip_runtime.h>

// ---------------------------------------------------------------------------
// RecurrentNet scan:
//   h' = tanh(U1_t + h@W1h + sigmoid(c@W1g)*h)
//   c' = sigmoid(U2_t + c@W2h) * tanh(h@W2g)
// 16 persistent WGs on XCD 0 (elected+probed); state via plain L2 stores with
// 16-slot rotation (L1-eviction-guaranteed).  ROUND 8: fully decoupled step --
// NO syncthreads in the loop; h-chain (w0,w3) and c-chain (w1,w2) handshake
// via 4 monotonic LDS tokens (acquire/release); one TCC poller per stream per
// WG on 128B-padded per-step counters with s_sleep backoff; producers post +1
// after their own vmcnt drain.  Fallback: round-2-proven MALL semantics.
// ---------------------------------------------------------------------------

typedef unsigned short u16;
typedef unsigned int   u32;
typedef __attribute__((ext_vector_type(8))) short s8v;   // 8 x bf16 (4 VGPR)
typedef __attribute__((ext_vector_type(4))) float f4v;

__device__ __forceinline__ u16 f2bf_rne(float f){
  u32 u = __float_as_uint(f);
  u32 r = u + 0x7fffu + ((u >> 16) & 1u);
  return (u16)(r >> 16);
}
__device__ __forceinline__ float bf2f(u16 h){ return __uint_as_float(((u32)h) << 16); }
__device__ __forceinline__ f4v MFMA(s8v a, s8v b, f4v c){
  return __builtin_amdgcn_mfma_f32_16x16x32_bf16(a, b, c, 0, 0, 0);
}
__device__ __forceinline__ float sigmoidf_(float x){ return 1.0f / (1.0f + __expf(-x)); }
__device__ __forceinline__ float tanh_fast(float x){
  float e = __expf(2.0f * x);           // inf->1, 0->-1 at the extremes
  return 1.0f - 2.0f / (e + 1.0f);
}

// CC=true: sc0 sc1 (MALL-coherent, round-2-proven). CC=false: plain (XCD-L2).
template<bool CC> __device__ __forceinline__ s8v ld16(const u16* p){
  s8v r;
  if (CC) asm volatile("global_load_dwordx4 %0, %1, off sc0 sc1" : "=v"(r) : "v"(p));
  else    asm volatile("global_load_dwordx4 %0, %1, off"         : "=v"(r) : "v"(p));
  return r;
}
template<bool CC> __device__ __forceinline__ void st2(u16* p, u32 v){
  if (CC) asm volatile("global_store_short %0, %1, off sc0 sc1" :: "v"(p), "v"(v) : "memory");
  else    asm volatile("global_store_short %0, %1, off"         :: "v"(p), "v"(v) : "memory");
}
__device__ __forceinline__ void store_dword_cc(u32* p, u32 v){
  asm volatile("global_store_dword %0, %1, off sc0 sc1" :: "v"(p), "v"(v) : "memory");
}
__device__ __forceinline__ void store_dword_plain_wait(u32* p, u32 v){
  asm volatile("global_store_dword %0, %1, off\n\ts_waitcnt vmcnt(0)"
               :: "v"(p), "v"(v) : "memory");
}
__device__ __forceinline__ u32 load_dword_plain_wait(const u32* p){
  u32 r;
  asm volatile("global_load_dword %0, %1, off\n\ts_waitcnt vmcnt(0)"
               : "=v"(r) : "v"(p));
  return r;
}

#define SEQT 1024
#define NWG  16
#define PROT 16                          // state rotation slots

// ws layout (bytes)
static const size_t OFF_U1  = 0;                      // f32 [1024][16][512]  32MB
static const size_t OFF_U2  = 33554432;               // bf16 [1024][16][512] 16MB
static const size_t OFF_WCT = OFF_U2 + 16777216;      // bf16 [1024][512] 1MB (dead after gemmk)
static const size_t OFF_ST  = OFF_WCT;                // ALIAS: u16 [16 slots][4][16][512] 1MB
static const size_t OFF_WT  = OFF_WCT + 1048576;      // bf16 [4][512][512] 2MB
static const size_t OFF_BC  = OFF_WT + 2097152;       // f32 [1024] (4KB)
static const size_t OFF_FL  = OFF_BC + 4096;          // u32 [1024][16] 64KB (CC mode)
static const size_t OFF_TOK = OFF_FL + 65536;         // u32 [16][16] tokens 4KB
static const size_t OFF_PRS = OFF_TOK + 4096;         // u32 [16][16] present 4KB
static const size_t OFF_CTL = OFF_PRS + 4096;         // u32 cnt@0, mode@16  4KB
static const size_t OFF_CN  = OFF_CTL + 4096;         // (unused) 4KB
static const size_t OFF_HCN = OFF_CN + 4096;          // u32 [1024][32] h-counters 128KB
static const size_t OFF_CCN = OFF_HCN + 131072;       // u32 [1024][32] c-counters 128KB

// --- Wcombt[n_g][i] = sum_k Wfc[i][k] * (Wx[k][n] + Wx[k+512][n]), bf16 ---
__global__ void wcombk(const float* __restrict__ Wfc, const float* __restrict__ W1x,
                       const float* __restrict__ W2x, u16* __restrict__ Wct){
  __shared__ float A[16][17], B[16][17];
  const float* Wx = blockIdx.z ? W2x : W1x;
  int i0 = blockIdx.y * 16, n0 = blockIdx.x * 16;
  int tx = threadIdx.x, ty = threadIdx.y;
  float acc = 0.f;
  for (int kc = 0; kc < 512; kc += 16){
    A[ty][tx] = Wfc[(size_t)(i0 + ty) * 512 + kc + tx];
    B[ty][tx] = Wx[(size_t)(kc + ty) * 512 + n0 + tx]
              + Wx[(size_t)(kc + ty + 512) * 512 + n0 + tx];
    __syncthreads();
    #pragma unroll
    for (int kk = 0; kk < 16; ++kk) acc += A[ty][kk] * B[kk][tx];
    __syncthreads();
  }
  Wct[(size_t)(blockIdx.z * 512 + n0 + tx) * 512 + i0 + ty] = f2bf_rne(acc);
}

// --- bc[n_g] = sum_k bfc[k]*(Wx[k][n]+Wx[k+512][n]), f32 ---
__global__ void bcombk(const float* __restrict__ bfc, const float* __restrict__ W1x,
                       const float* __restrict__ W2x, float* __restrict__ bc){
  int n = blockIdx.x * 256 + threadIdx.x;            // 0..1023
  const float* Wx = (n < 512) ? W1x : W2x;
  int nl = n & 511;
  float acc = 0.f;
  for (int k = 0; k < 512; ++k)
    acc += bfc[k] * (Wx[(size_t)k * 512 + nl] + Wx[(size_t)(k + 512) * 512 + nl]);
  bc[n] = acc;
}

// --- Wt[m][n][k] = bf16(Wm[k][n]) for m in {W1h,W1g,W2h,W2g} ---
__global__ void wtk(const float* __restrict__ A, const float* __restrict__ B,
                    const float* __restrict__ C, const float* __restrict__ D,
                    u16* __restrict__ Wt){
  __shared__ float tile[32][33];
  const float* src = (blockIdx.z == 0) ? A : (blockIdx.z == 1) ? B
                    : (blockIdx.z == 2) ? C : D;
  int n0 = blockIdx.x * 32, k0 = blockIdx.y * 32;
  for (int i = threadIdx.y; i < 32; i += 8)
    tile[i][threadIdx.x] = src[(size_t)(k0 + i) * 512 + n0 + threadIdx.x];
  __syncthreads();
  for (int i = threadIdx.y; i < 32; i += 8)
    Wt[(size_t)blockIdx.z * 262144 + (size_t)(n0 + i) * 512 + k0 + threadIdx.x]
        = f2bf_rne(tile[threadIdx.x][i]);
}

// --- U GEMM: [16384,512] x [512,1024] ; A = x split to bf16 hi+lo (2 passes) ---
__global__ __launch_bounds__(256) void gemmk(
    const float* __restrict__ x, const u16* __restrict__ Wct,
    const float* __restrict__ bc, float* __restrict__ U1, u16* __restrict__ U2){
  int l = threadIdx.x & 63, w = threadIdx.x >> 6;
  int lr = l & 15, lk = l >> 4;
  int m0 = blockIdx.y * 128 + (w & 1) * 64;
  int n0 = blockIdx.x * 64 + (w >> 1) * 32;
  f4v acc[4][2] = {};
  for (int ks = 0; ks < 16; ++ks){
    int k0 = ks * 32 + lk * 8;
    s8v bh0 = *(const s8v*)(Wct + (size_t)(n0 + lr) * 512 + k0);
    s8v bh1 = *(const s8v*)(Wct + (size_t)(n0 + 16 + lr) * 512 + k0);
    #pragma unroll
    for (int mi = 0; mi < 4; ++mi){
      const float* xp = x + (size_t)(m0 + mi * 16 + lr) * 512 + k0;
      f4v v0 = *(const f4v*)xp;
      f4v v1 = *(const f4v*)(xp + 4);
      s8v ah, al;
      #pragma unroll
      for (int j = 0; j < 4; ++j){
        { u32 u = __float_as_uint(v0[j]); ah[j] = (short)(u >> 16);
          float lof = v0[j] - __uint_as_float(u & 0xffff0000u);
          al[j] = (short)(__float_as_uint(lof) >> 16); }
        { u32 u = __float_as_uint(v1[j]); ah[j + 4] = (short)(u >> 16);
          float lof = v1[j] - __uint_as_float(u & 0xffff0000u);
          al[j + 4] = (short)(__float_as_uint(lof) >> 16); }
      }
      acc[mi][0] = MFMA(ah, bh0, acc[mi][0]);
      acc[mi][0] = MFMA(al, bh0, acc[mi][0]);
      acc[mi][1] = MFMA(ah, bh1, acc[mi][1]);
      acc[mi][1] = MFMA(al, bh1, acc[mi][1]);
    }
  }
  #pragma unroll
  for (int mi = 0; mi < 4; ++mi)
    #pragma unroll
    for (int ni = 0; ni < 2; ++ni){
      int n = n0 + ni * 16 + lr;
      float badd = bc[n];
      #pragma unroll
      for (int j = 0; j < 4; ++j){
        int r = m0 + mi * 16 + lk * 4 + j;        // C/D: row=(l>>4)*4+j, col=l&15
        int b = r >> 10, t = r & 1023;
        size_t oi = (size_t)(t * 16 + b) * 512;
        float v = acc[mi][ni][j] + badd;
        if (n < 512) U1[oi + n] = v;
        else         U2[oi + n - 512] = f2bf_rne(v);
      }
    }
}

// global counter poll: 1 RMW lane, non-identity add, sleep backoff
__device__ __forceinline__ void poll_cnt(u32* p, u32 need, int l){
  int g = 0;
  for (;;){
    u32 v = 0;
    if (l == 0)
      v = __hip_atomic_fetch_add(p, 0x10000u, __ATOMIC_RELAXED,
                                 __HIP_MEMORY_SCOPE_WORKGROUP);
    v = __builtin_amdgcn_readfirstlane(v);
    if ((v & 0xffffu) >= need) break;
    if (++g > 4000000) break;            // loud failure, never silent
    __builtin_amdgcn_s_sleep(1);
  }
}
// LDS token ops (monotonic, value = t+1)
__device__ __forceinline__ void tok_store(u32* tok, u32 v){
  __hip_atomic_store(tok, v, __ATOMIC_RELEASE, __HIP_MEMORY_SCOPE_WORKGROUP);
}
__device__ __forceinline__ void spin_tok(u32* tok, u32 need){
  int g = 0;
  while (__hip_atomic_load(tok, __ATOMIC_ACQUIRE, __HIP_MEMORY_SCOPE_WORKGROUP) < need){
    if (++g > 16000000) break;
  }
}

// --- FAST scan: no syncthreads; LDS-token chains + padded TCC counters ---
__device__ __forceinline__ void scan_fast(
    int wg, int tid,
    const float* __restrict__ U1, const u16* __restrict__ U2,
    const u16* __restrict__ Wt, u16* __restrict__ st,
    u32* __restrict__ hcnt, u32* __restrict__ ccnt,
    float* __restrict__ out, float* xg, float* xt, u32* ltok){
  const int w = tid >> 6, l = tid & 63;      // wave 0:W1h 1:W1g 2:W2h 3:W2g
  const int lr = l & 15, lk = l >> 4;
  const int ncol0 = wg * 32 + lr;

  s8v bf0[16], bf1[16];
  {
    const u16* Wm = Wt + (size_t)w * (512 * 512);
    #pragma unroll
    for (int ks = 0; ks < 16; ++ks){
      bf0[ks] = *(const s8v*)(Wm + (size_t)ncol0 * 512 + ks * 32 + lk * 8);
      bf1[ks] = *(const s8v*)(Wm + (size_t)(ncol0 + 16) * 512 + ks * 32 + lk * 8);
    }
  }
  const bool useH = (w == 0) || (w == 3);
  float hp0[4] = {0, 0, 0, 0}, hp1[4] = {0, 0, 0, 0};

  // U register double-buffer (w0: f32, w2: raw bf16)
  float un0[4], un1[4], uc0[4], uc1[4];
  u32   ur0[4], ur1[4];
  if (w == 0){
    #pragma unroll
    for (int j = 0; j < 4; ++j){
      size_t ro = (size_t)(lk * 4 + j) * 512;
      un0[j] = U1[ro + ncol0];
      un1[j] = U1[ro + ncol0 + 16];
    }
  } else if (w == 2){
    #pragma unroll
    for (int j = 0; j < 4; ++j){
      size_t ro = (size_t)(lk * 4 + j) * 512;
      ur0[j] = U2[ro + ncol0];
      ur1[j] = U2[ro + ncol0 + 16];
    }
  }

  for (int t = 0; t < SEQT; ++t){
    // ---- entry sync (no syncthreads) ----
    if (w == 0){
      if (t > 0) poll_cnt(hcnt + (size_t)(t - 1) * 32, NWG, l);
      tok_store(ltok + 0, (u32)(t + 1));       // h_ready
    } else if (w == 2){
      if (t > 0) poll_cnt(ccnt + (size_t)(t - 1) * 32, NWG, l);
      tok_store(ltok + 1, (u32)(t + 1));       // c_ready
    } else if (w == 3){
      spin_tok(ltok + 0, (u32)(t + 1));        // needs h
    } else {
      spin_tok(ltok + 1, (u32)(t + 1));        // needs c
    }
    __builtin_amdgcn_sched_barrier(0);

    // ---- state load from rotation slot t%PROT ----
    u16* rb = st + (size_t)(t & (PROT - 1)) * 32768 + (useH ? 0 : 16384);
    s8v ah[16], al[16];
    {
      u16* bhp = rb + lr * 512 + lk * 8;
      u16* blp = rb + 8192 + lr * 512 + lk * 8;
      #pragma unroll
      for (int ks = 0; ks < 16; ++ks){
        ah[ks] = ld16<false>(bhp + ks * 32);
        al[ks] = ld16<false>(blp + ks * 32);
      }
    }
    asm volatile("s_waitcnt vmcnt(0)" ::: "memory");   // also retires U loads
    __builtin_amdgcn_sched_barrier(0);

    if (w == 0){
      #pragma unroll
      for (int j = 0; j < 4; ++j){ uc0[j] = un0[j]; uc1[j] = un1[j]; }
    } else if (w == 2){
      #pragma unroll
      for (int j = 0; j < 4; ++j){
        uc0[j] = __uint_as_float(ur0[j] << 16);
        uc1[j] = __uint_as_float(ur1[j] << 16);
      }
    }

    f4v a0 = {0, 0, 0, 0}, a1 = {0, 0, 0, 0};
    f4v b0 = {0, 0, 0, 0}, b1 = {0, 0, 0, 0};
    #pragma unroll
    for (int ks = 0; ks < 16; ++ks){
      a0 = MFMA(ah[ks], bf0[ks], a0);
      a1 = MFMA(ah[ks], bf1[ks], a1);
      b0 = MFMA(al[ks], bf0[ks], b0);
      b1 = MFMA(al[ks], bf1[ks], b1);
    }
    #pragma unroll
    for (int j = 0; j < 4; ++j){ a0[j] += b0[j]; a1[j] += b1[j]; }

    const int par = t & 1;
    u16* wb = st + (size_t)((t + 1) & (PROT - 1)) * 32768;
    const int tn = (t + 1 < SEQT) ? t + 1 : t;

    if (w == 1){
      #pragma unroll
      for (int j = 0; j < 4; ++j){
        xg[((par * 2 + 0) * 16 + lk * 4 + j) * 16 + lr] = sigmoidf_(a0[j]);
        xg[((par * 2 + 1) * 16 + lk * 4 + j) * 16 + lr] = sigmoidf_(a1[j]);
      }
      tok_store(ltok + 2, (u32)(t + 1));       // xg_ready
    } else if (w == 3){
      #pragma unroll
      for (int j = 0; j < 4; ++j){
        xt[((par * 2 + 0) * 16 + lk * 4 + j) * 16 + lr] = tanh_fast(a0[j]);
        xt[((par * 2 + 1) * 16 + lk * 4 + j) * 16 + lr] = tanh_fast(a1[j]);
      }
      tok_store(ltok + 3, (u32)(t + 1));       // xt_ready
    } else if (w == 0){
      spin_tok(ltok + 2, (u32)(t + 1));
      __builtin_amdgcn_sched_barrier(0);
      float hn0v[4], hn1v[4];
      #pragma unroll
      for (int j = 0; j < 4; ++j){
        int b = lk * 4 + j;
        float hn0 = tanh_fast(uc0[j] + a0[j] + xg[((par * 2 + 0) * 16 + b) * 16 + lr] * hp0[j]);
        float hn1 = tanh_fast(uc1[j] + a1[j] + xg[((par * 2 + 1) * 16 + b) * 16 + lr] * hp1[j]);
        hp0[j] = hn0; hp1[j] = hn1;
        hn0v[j] = hn0; hn1v[j] = hn1;
        u32 u0 = __float_as_uint(hn0), u1 = __float_as_uint(hn1);
        int bi = b * 512;
        st2<false>(wb + bi + ncol0,      u0 >> 16);
        st2<false>(wb + bi + ncol0 + 16, u1 >> 16);
        float lo0 = hn0 - __uint_as_float(u0 & 0xffff0000u);
        float lo1 = hn1 - __uint_as_float(u1 & 0xffff0000u);
        st2<false>(wb + 8192 + bi + ncol0,      __float_as_uint(lo0) >> 16);
        st2<false>(wb + 8192 + bi + ncol0 + 16, __float_as_uint(lo1) >> 16);
      }
      #pragma unroll
      for (int j = 0; j < 4; ++j){
        size_t ro = (size_t)(tn * 16 + lk * 4 + j) * 512;
        un0[j] = U1[ro + ncol0];
        un1[j] = U1[ro + ncol0 + 16];
      }
      asm volatile("s_waitcnt vmcnt(8)" ::: "memory");  // 16 state stores done
      if (l == 0)
        __hip_atomic_fetch_add(hcnt + (size_t)t * 32, 1u,
                               __ATOMIC_RELAXED, __HIP_MEMORY_SCOPE_WORKGROUP);
      #pragma unroll
      for (int j = 0; j < 4; ++j){
        int b = lk * 4 + j;
        size_t ob = (size_t)b * (SEQT * 512) + (size_t)t * 512;
        out[ob + ncol0]      = hn0v[j];
        out[ob + ncol0 + 16] = hn1v[j];
        if (t == SEQT - 1){
          out[8388608 + (size_t)b * 512 + ncol0]      = hn0v[j];
          out[8388608 + (size_t)b * 512 + ncol0 + 16] = hn1v[j];
        }
      }
    } else { // w == 2
      spin_tok(ltok + 3, (u32)(t + 1));
      __builtin_amdgcn_sched_barrier(0);
      float cn0v[4], cn1v[4];
      #pragma unroll
      for (int j = 0; j < 4; ++j){
        int b = lk * 4 + j;
        float cn0 = sigmoidf_(uc0[j] + a0[j]) * xt[((par * 2 + 0) * 16 + b) * 16 + lr];
        float cn1 = sigmoidf_(uc1[j] + a1[j]) * xt[((par * 2 + 1) * 16 + b) * 16 + lr];
        cn0v[j] = cn0; cn1v[j] = cn1;
        u32 u0 = __float_as_uint(cn0), u1 = __float_as_uint(cn1);
        int bi = b * 512;
        st2<false>(wb + 16384 + bi + ncol0,      u0 >> 16);
        st2<false>(wb + 16384 + bi + ncol0 + 16, u1 >> 16);
        float lo0 = cn0 - __uint_as_float(u0 & 0xffff0000u);
        float lo1 = cn1 - __uint_as_float(u1 & 0xffff0000u);
        st2<false>(wb + 24576 + bi + ncol0,      __float_as_uint(lo0) >> 16);
        st2<false>(wb + 24576 + bi + ncol0 + 16, __float_as_uint(lo1) >> 16);
      }
      #pragma unroll
      for (int j = 0; j < 4; ++j){
        size_t ro = (size_t)(tn * 16 + lk * 4 + j) * 512;
        ur0[j] = U2[ro + ncol0];
        ur1[j] = U2[ro + ncol0 + 16];
      }
      asm volatile("s_waitcnt vmcnt(8)" ::: "memory");
      if (l == 0)
        __hip_atomic_fetch_add(ccnt + (size_t)t * 32, 1u,
                               __ATOMIC_RELAXED, __HIP_MEMORY_SCOPE_WORKGROUP);
      if (t == SEQT - 1){
        #pragma unroll
        for (int j = 0; j < 4; ++j){
          int b = lk * 4 + j;
          out[8396800 + (size_t)b * 512 + ncol0]      = cn0v[j];
          out[8396800 + (size_t)b * 512 + ncol0 + 16] = cn1v[j];
        }
      }
    }
  }
}

// --- CC fallback scan (round-2/6-proven MALL path), used for modes 2/3 ---
__device__ __forceinline__ void scan_cc(
    int wg, int tid,
    const float* __restrict__ U1, const u16* __restrict__ U2,
    const u16* __restrict__ Wt, u16* __restrict__ st,
    u32* __restrict__ flags, float* __restrict__ out, float* xg, float* xt){
  const int w = tid >> 6, l = tid & 63;
  const int lr = l & 15, lk = l >> 4;
  const int ncol0 = wg * 32 + lr;
  s8v bf0[16], bf1[16];
  {
    const u16* Wm = Wt + (size_t)w * (512 * 512);
    #pragma unroll
    for (int ks = 0; ks < 16; ++ks){
      bf0[ks] = *(const s8v*)(Wm + (size_t)ncol0 * 512 + ks * 32 + lk * 8);
      bf1[ks] = *(const s8v*)(Wm + (size_t)(ncol0 + 16) * 512 + ks * 32 + lk * 8);
    }
  }
  const bool useH = (w == 0) || (w == 3);
  float hp0[4] = {0, 0, 0, 0}, hp1[4] = {0, 0, 0, 0};
  long guard = 0;
  for (int t = 0; t < SEQT; ++t){
    float uu0[4], uu1[4];
    if (w == 0){
      #pragma unroll
      for (int j = 0; j < 4; ++j){
        size_t ro = (size_t)(t * 16 + lk * 4 + j) * 512;
        uu0[j] = U1[ro + ncol0];
        uu1[j] = U1[ro + ncol0 + 16];
      }
    } else if (w == 2){
      #pragma unroll
      for (int j = 0; j < 4; ++j){
        size_t ro = (size_t)(t * 16 + lk * 4 + j) * 512;
        uu0[j] = bf2f(U2[ro + ncol0]);
        uu1[j] = bf2f(U2[ro + ncol0 + 16]);
      }
    }
    if (t > 0){
      const u32* fl = flags + (size_t)(t - 1) * NWG;
      for (;;){
        u32 v = 1u;
        if (l < NWG) v = __hip_atomic_load(fl + l, __ATOMIC_RELAXED, __HIP_MEMORY_SCOPE_AGENT);
        if (__all(v != 0u)) break;
        if (++guard > 1000000L) break;
      }
      __builtin_amdgcn_sched_barrier(0);
    }
    u16* rb = st + (size_t)(t & (PROT - 1)) * 32768 + (useH ? 0 : 16384);
    s8v ah[16], al[16];
    {
      u16* bhp = rb + lr * 512 + lk * 8;
      u16* blp = rb + 8192 + lr * 512 + lk * 8;
      #pragma unroll
      for (int ks = 0; ks < 16; ++ks){
        ah[ks] = ld16<true>(bhp + ks * 32);
        al[ks] = ld16<true>(blp + ks * 32);
      }
    }
    asm volatile("s_waitcnt vmcnt(0)" ::: "memory");
    __builtin_amdgcn_sched_barrier(0);
    f4v a0 = {0, 0, 0, 0}, a1 = {0, 0, 0, 0};
    f4v b0 = {0, 0, 0, 0}, b1 = {0, 0, 0, 0};
    #pragma unroll
    for (int ks = 0; ks < 16; ++ks){
      a0 = MFMA(ah[ks], bf0[ks], a0);
      a1 = MFMA(ah[ks], bf1[ks], a1);
      b0 = MFMA(al[ks], bf0[ks], b0);
      b1 = MFMA(al[ks], bf1[ks], b1);
    }
    #pragma unroll
    for (int j = 0; j < 4; ++j){ a0[j] += b0[j]; a1[j] += b1[j]; }
    if (w == 1){
      #pragma unroll
      for (int j = 0; j < 4; ++j){
        xg[(0 * 16 + lk * 4 + j) * 16 + lr] = sigmoidf_(a0[j]);
        xg[(1 * 16 + lk * 4 + j) * 16 + lr] = sigmoidf_(a1[j]);
      }
    } else if (w == 3){
      #pragma unroll
      for (int j = 0; j < 4; ++j){
        xt[(0 * 16 + lk * 4 + j) * 16 + lr] = tanh_fast(a0[j]);
        xt[(1 * 16 + lk * 4 + j) * 16 + lr] = tanh_fast(a1[j]);
      }
    }
    __syncthreads();
    u16* wb = st + (size_t)((t + 1) & (PROT - 1)) * 32768;
    float hn0v[4], hn1v[4], cn0v[4], cn1v[4];
    if (w == 0){
      #pragma unroll
      for (int j = 0; j < 4; ++j){
        int b = lk * 4 + j;
        float hn0 = tanh_fast(uu0[j] + a0[j] + xg[(0 * 16 + b) * 16 + lr] * hp0[j]);
        float hn1 = tanh_fast(uu1[j] + a1[j] + xg[(1 * 16 + b) * 16 + lr] * hp1[j]);
        hp0[j] = hn0; hp1[j] = hn1;
        hn0v[j] = hn0; hn1v[j] = hn1;
        u32 u0 = __float_as_uint(hn0), u1 = __float_as_uint(hn1);
        int bi = b * 512;
        st2<true>(wb + bi + ncol0,      u0 >> 16);
        st2<true>(wb + bi + ncol0 + 16, u1 >> 16);
        float lo0 = hn0 - __uint_as_float(u0 & 0xffff0000u);
        float lo1 = hn1 - __uint_as_float(u1 & 0xffff0000u);
        st2<true>(wb + 8192 + bi + ncol0,      __float_as_uint(lo0) >> 16);
        st2<true>(wb + 8192 + bi + ncol0 + 16, __float_as_uint(lo1) >> 16);
      }
      asm volatile("s_waitcnt vmcnt(0)" ::: "memory");
    } else if (w == 2){
      #pragma unroll
      for (int j = 0; j < 4; ++j){
        int b = lk * 4 + j;
        float cn0 = sigmoidf_(uu0[j] + a0[j]) * xt[(0 * 16 + b) * 16 + lr];
        float cn1 = sigmoidf_(uu1[j] + a1[j]) * xt[(1 * 16 + b) * 16 + lr];
        cn0v[j] = cn0; cn1v[j] = cn1;
        u32 u0 = __float_as_uint(cn0), u1 = __float_as_uint(cn1);
        int bi = b * 512;
        st2<true>(wb + 16384 + bi + ncol0,      u0 >> 16);
        st2<true>(wb + 16384 + bi + ncol0 + 16, u1 >> 16);
        float lo0 = cn0 - __uint_as_float(u0 & 0xffff0000u);
        float lo1 = cn1 - __uint_as_float(u1 & 0xffff0000u);
        st2<true>(wb + 24576 + bi + ncol0,      __float_as_uint(lo0) >> 16);
        st2<true>(wb + 24576 + bi + ncol0 + 16, __float_as_uint(lo1) >> 16);
      }
      asm volatile("s_waitcnt vmcnt(0)" ::: "memory");
    }
    __syncthreads();
    if (tid == 0) store_dword_cc(flags + (size_t)t * NWG + wg, 1u);
    if (w == 0){
      #pragma unroll
      for (int j = 0; j < 4; ++j){
        int b = lk * 4 + j;
        size_t ob = (size_t)b * (SEQT * 512) + (size_t)t * 512;
        out[ob + ncol0]      = hn0v[j];
        out[ob + ncol0 + 16] = hn1v[j];
        if (t == SEQT - 1){
          out[8388608 + (size_t)b * 512 + ncol0]      = hn0v[j];
          out[8388608 + (size_t)b * 512 + ncol0 + 16] = hn1v[j];
        }
      }
    } else if (w == 2 && t == SEQT - 1){
      #pragma unroll
      for (int j = 0; j < 4; ++j){
        int b = lk * 4 + j;
        out[8396800 + (size_t)b * 512 + ncol0]      = cn0v[j];
        out[8396800 + (size_t)b * 512 + ncol0 + 16] = cn1v[j];
      }
    }
  }
}

// --- persistent scan: election onto XCD0 + coherence probe + fallback ---
__global__ __launch_bounds__(256, 1) void recurk(
    const float* __restrict__ U1, const u16* __restrict__ U2,
    const u16* __restrict__ Wt, u16* __restrict__ st,
    u32* __restrict__ flags, u32* __restrict__ hcnt, u32* __restrict__ ccnt,
    u32* __restrict__ tok, u32* __restrict__ prs,
    u32* __restrict__ ctl, float* __restrict__ out){
  const int tid = threadIdx.x;
  __shared__ int slot_sh, mode_sh;
  __shared__ float xg[4 * 16 * 16], xt[4 * 16 * 16];
  __shared__ u32 ltok[4];
  u32* cntp  = ctl;
  u32* modep = ctl + 16;

  if (tid == 0){
    int s = -1;
    u32 xcc;
    asm volatile("s_getreg_b32 %0, hwreg(HW_REG_XCC_ID)" : "=s"(xcc));
    if ((xcc & 0xfu) == 0u)
      s = (int)__hip_atomic_fetch_add(cntp, 1u, __ATOMIC_RELAXED,
                                      __HIP_MEMORY_SCOPE_AGENT);
    slot_sh = s;
  }
  __syncthreads();
  const int slot = slot_sh;

  if (tid == 0){
    if (slot >= 0 && slot < NWG){
      store_dword_plain_wait(tok + slot * 16, 0x5A5A0000u + (u32)slot);
      __hip_atomic_store(prs + slot * 16, 1u, __ATOMIC_RELAXED,
                         __HIP_MEMORY_SCOPE_AGENT);
    }
    if (blockIdx.x == 0){
      long g = 0;
      for (;;){
        u32 c = __hip_atomic_load(cntp, __ATOMIC_RELAXED, __HIP_MEMORY_SCOPE_AGENT);
        if (c >= NWG) break;
        if (++g > 2000000L){ atomicCAS(modep, 0u, 2u); break; }
      }
    }
    if (slot == 0){
      bool ok = true;
      long g = 0;
      for (int s2 = 1; s2 < NWG && ok; ++s2){
        for (;;){
          u32 p = __hip_atomic_load(prs + s2 * 16, __ATOMIC_RELAXED,
                                    __HIP_MEMORY_SCOPE_AGENT);
          if (p) break;
          if (++g > 5000000L){ ok = false; break; }
        }
      }
      if (ok){
        for (int s2 = 1; s2 < NWG; ++s2){
          u32 v = load_dword_plain_wait(tok + s2 * 16);
          if (v != 0x5A5A0000u + (u32)s2){ ok = false; break; }
        }
      }
      atomicCAS(modep, 0u, ok ? 1u : 3u);
    }
    long g = 0;
    u32 m;
    for (;;){
      m = __hip_atomic_load(modep, __ATOMIC_RELAXED, __HIP_MEMORY_SCOPE_AGENT);
      if (m) break;
      if (++g > 50000000L){ m = 3u; break; }
    }
    mode_sh = (int)m;
  }
  if (tid < 4) ltok[tid] = 0;
  __syncthreads();
  const int mode = mode_sh;

  int wg; bool part;
  if (mode == 2){ wg = blockIdx.x; part = (wg < NWG); }
  else          { wg = slot;       part = (slot >= 0 && slot < NWG); }
  if (!part) return;

  if (mode == 1) scan_fast(wg, tid, U1, U2, Wt, st, hcnt, ccnt, out, xg, xt, ltok);
  else           scan_cc (wg, tid, U1, U2, Wt, st, flags, out, xg, xt);
}

extern "C" void kernel_launch(void* const* d_in, const int* in_sizes, int n_in,
                              void* d_out, int out_size, void* d_ws, size_t ws_size,
                              hipStream_t stream){
  const float* x   = (const float*)d_in[0];
  const float* Wfc = (const float*)d_in[1];
  const float* bfc = (const float*)d_in[2];
  const float* W1x = (const float*)d_in[3];
  const float* W1h = (const float*)d_in[4];
  const float* W1g = (const float*)d_in[5];
  const float* W2x = (const float*)d_in[6];
  const float* W2h = (const float*)d_in[7];
  const float* W2g = (const float*)d_in[8];

  char* ws = (char*)d_ws;
  float* U1   = (float*)(ws + OFF_U1);
  u16*   U2   = (u16*)  (ws + OFF_U2);
  u16*   Wct  = (u16*)  (ws + OFF_WCT);
  u16*   st   = (u16*)  (ws + OFF_ST);     // aliases Wct (dead after gemmk)
  u16*   Wt   = (u16*)  (ws + OFF_WT);
  float* bc   = (float*)(ws + OFF_BC);
  u32*   flags= (u32*)  (ws + OFF_FL);
  u32*   tok  = (u32*)  (ws + OFF_TOK);
  u32*   prs  = (u32*)  (ws + OFF_PRS);
  u32*   ctl  = (u32*)  (ws + OFF_CTL);
  u32*   hcnt = (u32*)  (ws + OFF_HCN);
  u32*   ccnt = (u32*)  (ws + OFF_CCN);
  float* out  = (float*)d_out;

  // zero CC flags + tokens + present + control every launch
  hipMemsetAsync(ws + OFF_FL, 0, 65536 + 4096 + 4096 + 4096 + 4096, stream);
  // zero padded step counters (h + c, 256 KB)
  hipMemsetAsync(ws + OFF_HCN, 0, 262144, stream);

  wcombk<<<dim3(32, 32, 2), dim3(16, 16), 0, stream>>>(Wfc, W1x, W2x, Wct);
  bcombk<<<dim3(4), dim3(256), 0, stream>>>(bfc, W1x, W2x, bc);
  wtk   <<<dim3(16, 16, 4), dim3(32, 8), 0, stream>>>(W1h, W1g, W2h, W2g, Wt);
  gemmk <<<dim3(16, 128), dim3(256), 0, stream>>>(x, Wct, bc, U1, U2);
  // Wct is dead now; zero the aliased state-rotation region (slot 0 = h0,c0)
  hipMemsetAsync(ws + OFF_ST, 0, 1048576, stream);
  recurk<<<dim3(256), dim3(256), 0, stream>>>(U1, U2, Wt, st, flags, hcnt, ccnt, tok, prs, ctl, out);
}

// Round 11
// 6230.322 us; speedup vs baseline: 1.1665x; 1.0011x over previous
//
#include <hip/hip_runtime.h>

// ---------------------------------------------------------------------------
// RecurrentNet scan:
//   h' = tanh(U1_t + h@W1h + sigmoid(c@W1g)*h)
//   c' = sigmoid(U2_t + c@W2h) * tanh(h@W2g)
// ROUND 11 = ROUND 8 (passing, 6237us) + HEATER ONLY (bisect r9/r10 crash:
// nt-vs-heater; also tests the DPM down-clock theory).  No nt ops anywhere.
// Heater = dependent FMAs + proven AGENT atomic done-poll + hard iteration
// bound.  16 persistent WGs on XCD 0; state via plain L2 (16-slot rotation);
// decoupled LDS-token/padded-counter sync.  Fallback: MALL semantics.
// ---------------------------------------------------------------------------

typedef unsigned short u16;
typedef unsigned int   u32;
typedef __attribute__((ext_vector_type(8))) short s8v;   // 8 x bf16 (4 VGPR)
typedef __attribute__((ext_vector_type(4))) float f4v;

__device__ __forceinline__ u16 f2bf_rne(float f){
  u32 u = __float_as_uint(f);
  u32 r = u + 0x7fffu + ((u >> 16) & 1u);
  return (u16)(r >> 16);
}
__device__ __forceinline__ float bf2f(u16 h){ return __uint_as_float(((u32)h) << 16); }
__device__ __forceinline__ f4v MFMA(s8v a, s8v b, f4v c){
  return __builtin_amdgcn_mfma_f32_16x16x32_bf16(a, b, c, 0, 0, 0);
}
__device__ __forceinline__ float sigmoidf_(float x){ return 1.0f / (1.0f + __expf(-x)); }
__device__ __forceinline__ float tanh_fast(float x){
  float e = __expf(2.0f * x);           // inf->1, 0->-1 at the extremes
  return 1.0f - 2.0f / (e + 1.0f);
}

// CC=true: sc0 sc1 (MALL-coherent, round-2-proven). CC=false: plain (XCD-L2).
template<bool CC> __device__ __forceinline__ s8v ld16(const u16* p){
  s8v r;
  if (CC) asm volatile("global_load_dwordx4 %0, %1, off sc0 sc1" : "=v"(r) : "v"(p));
  else    asm volatile("global_load_dwordx4 %0, %1, off"         : "=v"(r) : "v"(p));
  return r;
}
template<bool CC> __device__ __forceinline__ void st2(u16* p, u32 v){
  if (CC) asm volatile("global_store_short %0, %1, off sc0 sc1" :: "v"(p), "v"(v) : "memory");
  else    asm volatile("global_store_short %0, %1, off"         :: "v"(p), "v"(v) : "memory");
}
__device__ __forceinline__ void store_dword_cc(u32* p, u32 v){
  asm volatile("global_store_dword %0, %1, off sc0 sc1" :: "v"(p), "v"(v) : "memory");
}
__device__ __forceinline__ void store_dword_plain_wait(u32* p, u32 v){
  asm volatile("global_store_dword %0, %1, off\n\ts_waitcnt vmcnt(0)"
               :: "v"(p), "v"(v) : "memory");
}
__device__ __forceinline__ u32 load_dword_plain_wait(const u32* p){
  u32 r;
  asm volatile("global_load_dword %0, %1, off\n\ts_waitcnt vmcnt(0)"
               : "=v"(r) : "v"(p));
  return r;
}

#define SEQT 1024
#define NWG  16
#define PROT 16                          // state rotation slots

// ws layout (bytes)
static const size_t OFF_U1  = 0;                      // f32 [1024][16][512]  32MB
static const size_t OFF_U2  = 33554432;               // bf16 [1024][16][512] 16MB
static const size_t OFF_WCT = OFF_U2 + 16777216;      // bf16 [1024][512] 1MB (dead after gemmk)
static const size_t OFF_ST  = OFF_WCT;                // ALIAS: u16 [16 slots][4][16][512] 1MB
static const size_t OFF_WT  = OFF_WCT + 1048576;      // bf16 [4][512][512] 2MB
static const size_t OFF_BC  = OFF_WT + 2097152;       // f32 [1024] (4KB)
static const size_t OFF_FL  = OFF_BC + 4096;          // u32 [1024][16] 64KB (CC mode)
static const size_t OFF_TOK = OFF_FL + 65536;         // u32 [16][16] tokens 4KB
static const size_t OFF_PRS = OFF_TOK + 4096;         // u32 [16][16] present 4KB
static const size_t OFF_CTL = OFF_PRS + 4096;         // u32 cnt@0, mode@16, done@64  4KB
static const size_t OFF_CN  = OFF_CTL + 4096;         // (unused) 4KB
static const size_t OFF_HCN = OFF_CN + 4096;          // u32 [1024][32] h-counters 128KB
static const size_t OFF_CCN = OFF_HCN + 131072;       // u32 [1024][32] c-counters 128KB

// --- Wcombt[n_g][i] = sum_k Wfc[i][k] * (Wx[k][n] + Wx[k+512][n]), bf16 ---
__global__ void wcombk(const float* __restrict__ Wfc, const float* __restrict__ W1x,
                       const float* __restrict__ W2x, u16* __restrict__ Wct){
  __shared__ float A[16][17], B[16][17];
  const float* Wx = blockIdx.z ? W2x : W1x;
  int i0 = blockIdx.y * 16, n0 = blockIdx.x * 16;
  int tx = threadIdx.x, ty = threadIdx.y;
  float acc = 0.f;
  for (int kc = 0; kc < 512; kc += 16){
    A[ty][tx] = Wfc[(size_t)(i0 + ty) * 512 + kc + tx];
    B[ty][tx] = Wx[(size_t)(kc + ty) * 512 + n0 + tx]
              + Wx[(size_t)(kc + ty + 512) * 512 + n0 + tx];
    __syncthreads();
    #pragma unroll
    for (int kk = 0; kk < 16; ++kk) acc += A[ty][kk] * B[kk][tx];
    __syncthreads();
  }
  Wct[(size_t)(blockIdx.z * 512 + n0 + tx) * 512 + i0 + ty] = f2bf_rne(acc);
}

// --- bc[n_g] = sum_k bfc[k]*(Wx[k][n]+Wx[k+512][n]), f32 ---
__global__ void bcombk(const float* __restrict__ bfc, const float* __restrict__ W1x,
                       const float* __restrict__ W2x, float* __restrict__ bc){
  int n = blockIdx.x * 256 + threadIdx.x;            // 0..1023
  const float* Wx = (n < 512) ? W1x : W2x;
  int nl = n & 511;
  float acc = 0.f;
  for (int k = 0; k < 512; ++k)
    acc += bfc[k] * (Wx[(size_t)k * 512 + nl] + Wx[(size_t)(k + 512) * 512 + nl]);
  bc[n] = acc;
}

// --- Wt[m][n][k] = bf16(Wm[k][n]) for m in {W1h,W1g,W2h,W2g} ---
__global__ void wtk(const float* __restrict__ A, const float* __restrict__ B,
                    const float* __restrict__ C, const float* __restrict__ D,
                    u16* __restrict__ Wt){
  __shared__ float tile[32][33];
  const float* src = (blockIdx.z == 0) ? A : (blockIdx.z == 1) ? B
                    : (blockIdx.z == 2) ? C : D;
  int n0 = blockIdx.x * 32, k0 = blockIdx.y * 32;
  for (int i = threadIdx.y; i < 32; i += 8)
    tile[i][threadIdx.x] = src[(size_t)(k0 + i) * 512 + n0 + threadIdx.x];
  __syncthreads();
  for (int i = threadIdx.y; i < 32; i += 8)
    Wt[(size_t)blockIdx.z * 262144 + (size_t)(n0 + i) * 512 + k0 + threadIdx.x]
        = f2bf_rne(tile[threadIdx.x][i]);
}

// --- U GEMM: [16384,512] x [512,1024] ; A = x split to bf16 hi+lo (2 passes) ---
__global__ __launch_bounds__(256) void gemmk(
    const float* __restrict__ x, const u16* __restrict__ Wct,
    const float* __restrict__ bc, float* __restrict__ U1, u16* __restrict__ U2){
  int l = threadIdx.x & 63, w = threadIdx.x >> 6;
  int lr = l & 15, lk = l >> 4;
  int m0 = blockIdx.y * 128 + (w & 1) * 64;
  int n0 = blockIdx.x * 64 + (w >> 1) * 32;
  f4v acc[4][2] = {};
  for (int ks = 0; ks < 16; ++ks){
    int k0 = ks * 32 + lk * 8;
    s8v bh0 = *(const s8v*)(Wct + (size_t)(n0 + lr) * 512 + k0);
    s8v bh1 = *(const s8v*)(Wct + (size_t)(n0 + 16 + lr) * 512 + k0);
    #pragma unroll
    for (int mi = 0; mi < 4; ++mi){
      const float* xp = x + (size_t)(m0 + mi * 16 + lr) * 512 + k0;
      f4v v0 = *(const f4v*)xp;
      f4v v1 = *(const f4v*)(xp + 4);
      s8v ah, al;
      #pragma unroll
      for (int j = 0; j < 4; ++j){
        { u32 u = __float_as_uint(v0[j]); ah[j] = (short)(u >> 16);
          float lof = v0[j] - __uint_as_float(u & 0xffff0000u);
          al[j] = (short)(__float_as_uint(lof) >> 16); }
        { u32 u = __float_as_uint(v1[j]); ah[j + 4] = (short)(u >> 16);
          float lof = v1[j] - __uint_as_float(u & 0xffff0000u);
          al[j + 4] = (short)(__float_as_uint(lof) >> 16); }
      }
      acc[mi][0] = MFMA(ah, bh0, acc[mi][0]);
      acc[mi][0] = MFMA(al, bh0, acc[mi][0]);
      acc[mi][1] = MFMA(ah, bh1, acc[mi][1]);
      acc[mi][1] = MFMA(al, bh1, acc[mi][1]);
    }
  }
  #pragma unroll
  for (int mi = 0; mi < 4; ++mi)
    #pragma unroll
    for (int ni = 0; ni < 2; ++ni){
      int n = n0 + ni * 16 + lr;
      float badd = bc[n];
      #pragma unroll
      for (int j = 0; j < 4; ++j){
        int r = m0 + mi * 16 + lk * 4 + j;        // C/D: row=(l>>4)*4+j, col=l&15
        int b = r >> 10, t = r & 1023;
        size_t oi = (size_t)(t * 16 + b) * 512;
        float v = acc[mi][ni][j] + badd;
        if (n < 512) U1[oi + n] = v;
        else         U2[oi + n - 512] = f2bf_rne(v);
      }
    }
}

// global counter poll: 1 RMW lane, non-identity add, sleep backoff
__device__ __forceinline__ void poll_cnt(u32* p, u32 need, int l){
  int g = 0;
  for (;;){
    u32 v = 0;
    if (l == 0)
      v = __hip_atomic_fetch_add(p, 0x10000u, __ATOMIC_RELAXED,
                                 __HIP_MEMORY_SCOPE_WORKGROUP);
    v = __builtin_amdgcn_readfirstlane(v);
    if ((v & 0xffffu) >= need) break;
    if (++g > 4000000) break;            // loud failure, never silent
    __builtin_amdgcn_s_sleep(1);
  }
}
// LDS token ops (monotonic, value = t+1)
__device__ __forceinline__ void tok_store(u32* tok, u32 v){
  __hip_atomic_store(tok, v, __ATOMIC_RELEASE, __HIP_MEMORY_SCOPE_WORKGROUP);
}
__device__ __forceinline__ void spin_tok(u32* tok, u32 need){
  int g = 0;
  while (__hip_atomic_load(tok, __ATOMIC_ACQUIRE, __HIP_MEMORY_SCOPE_WORKGROUP) < need){
    if (++g > 16000000) break;
  }
}

// --- heater: keep DPM clocks up on the 240 non-elected CUs ---
// Only proven primitives: VOP2 FMA asm + AGENT atomic done-poll (round-2/4
// mechanism) + hard iteration bound (~17ms @2.4GHz worst case, loud not hung).
__device__ __forceinline__ void heater(const u32* done){
  float a0 = 1.0f + (float)(threadIdx.x & 7) * 1e-7f;
  float a1 = 1.5f;
  float m = 0.9999999f, b = 1e-7f;
  for (int it = 0; it < 600000; ++it){
    #pragma unroll
    for (int k = 0; k < 32; ++k){
      asm volatile("v_fmac_f32 %0, %2, %3\n\tv_fmac_f32 %1, %2, %3"
                   : "+v"(a0), "+v"(a1) : "v"(m), "v"(b));
    }
    if ((it & 15) == 0){
      if (__hip_atomic_load(done, __ATOMIC_RELAXED, __HIP_MEMORY_SCOPE_AGENT) != 0u)
        break;
    }
  }
  asm volatile("" :: "v"(a0), "v"(a1));           // keep live
}

// --- FAST scan: no syncthreads; LDS-token chains + padded TCC counters ---
__device__ __forceinline__ void scan_fast(
    int wg, int tid,
    const float* __restrict__ U1, const u16* __restrict__ U2,
    const u16* __restrict__ Wt, u16* __restrict__ st,
    u32* __restrict__ hcnt, u32* __restrict__ ccnt,
    float* __restrict__ out, float* xg, float* xt, u32* ltok){
  const int w = tid >> 6, l = tid & 63;      // wave 0:W1h 1:W1g 2:W2h 3:W2g
  const int lr = l & 15, lk = l >> 4;
  const int ncol0 = wg * 32 + lr;

  s8v bf0[16], bf1[16];
  {
    const u16* Wm = Wt + (size_t)w * (512 * 512);
    #pragma unroll
    for (int ks = 0; ks < 16; ++ks){
      bf0[ks] = *(const s8v*)(Wm + (size_t)ncol0 * 512 + ks * 32 + lk * 8);
      bf1[ks] = *(const s8v*)(Wm + (size_t)(ncol0 + 16) * 512 + ks * 32 + lk * 8);
    }
  }
  const bool useH = (w == 0) || (w == 3);
  float hp0[4] = {0, 0, 0, 0}, hp1[4] = {0, 0, 0, 0};

  // U register double-buffer (w0: f32, w2: raw bf16)
  float un0[4], un1[4], uc0[4], uc1[4];
  u32   ur0[4], ur1[4];
  if (w == 0){
    #pragma unroll
    for (int j = 0; j < 4; ++j){
      size_t ro = (size_t)(lk * 4 + j) * 512;
      un0[j] = U1[ro + ncol0];
      un1[j] = U1[ro + ncol0 + 16];
    }
  } else if (w == 2){
    #pragma unroll
    for (int j = 0; j < 4; ++j){
      size_t ro = (size_t)(lk * 4 + j) * 512;
      ur0[j] = U2[ro + ncol0];
      ur1[j] = U2[ro + ncol0 + 16];
    }
  }

  for (int t = 0; t < SEQT; ++t){
    // ---- entry sync (no syncthreads) ----
    if (w == 0){
      if (t > 0) poll_cnt(hcnt + (size_t)(t - 1) * 32, NWG, l);
      tok_store(ltok + 0, (u32)(t + 1));       // h_ready
    } else if (w == 2){
      if (t > 0) poll_cnt(ccnt + (size_t)(t - 1) * 32, NWG, l);
      tok_store(ltok + 1, (u32)(t + 1));       // c_ready
    } else if (w == 3){
      spin_tok(ltok + 0, (u32)(t + 1));        // needs h
    } else {
      spin_tok(ltok + 1, (u32)(t + 1));        // needs c
    }
    __builtin_amdgcn_sched_barrier(0);

    // ---- state load from rotation slot t%PROT ----
    u16* rb = st + (size_t)(t & (PROT - 1)) * 32768 + (useH ? 0 : 16384);
    s8v ah[16], al[16];
    {
      u16* bhp = rb + lr * 512 + lk * 8;
      u16* blp = rb + 8192 + lr * 512 + lk * 8;
      #pragma unroll
      for (int ks = 0; ks < 16; ++ks){
        ah[ks] = ld16<false>(bhp + ks * 32);
        al[ks] = ld16<false>(blp + ks * 32);
      }
    }
    asm volatile("s_waitcnt vmcnt(0)" ::: "memory");   // also retires U loads
    __builtin_amdgcn_sched_barrier(0);

    if (w == 0){
      #pragma unroll
      for (int j = 0; j < 4; ++j){ uc0[j] = un0[j]; uc1[j] = un1[j]; }
    } else if (w == 2){
      #pragma unroll
      for (int j = 0; j < 4; ++j){
        uc0[j] = __uint_as_float(ur0[j] << 16);
        uc1[j] = __uint_as_float(ur1[j] << 16);
      }
    }

    f4v a0 = {0, 0, 0, 0}, a1 = {0, 0, 0, 0};
    f4v b0 = {0, 0, 0, 0}, b1 = {0, 0, 0, 0};
    #pragma unroll
    for (int ks = 0; ks < 16; ++ks){
      a0 = MFMA(ah[ks], bf0[ks], a0);
      a1 = MFMA(ah[ks], bf1[ks], a1);
      b0 = MFMA(al[ks], bf0[ks], b0);
      b1 = MFMA(al[ks], bf1[ks], b1);
    }
    #pragma unroll
    for (int j = 0; j < 4; ++j){ a0[j] += b0[j]; a1[j] += b1[j]; }

    const int par = t & 1;
    u16* wb = st + (size_t)((t + 1) & (PROT - 1)) * 32768;
    const int tn = (t + 1 < SEQT) ? t + 1 : t;

    if (w == 1){
      #pragma unroll
      for (int j = 0; j < 4; ++j){
        xg[((par * 2 + 0) * 16 + lk * 4 + j) * 16 + lr] = sigmoidf_(a0[j]);
        xg[((par * 2 + 1) * 16 + lk * 4 + j) * 16 + lr] = sigmoidf_(a1[j]);
      }
      tok_store(ltok + 2, (u32)(t + 1));       // xg_ready
    } else if (w == 3){
      #pragma unroll
      for (int j = 0; j < 4; ++j){
        xt[((par * 2 + 0) * 16 + lk * 4 + j) * 16 + lr] = tanh_fast(a0[j]);
        xt[((par * 2 + 1) * 16 + lk * 4 + j) * 16 + lr] = tanh_fast(a1[j]);
      }
      tok_store(ltok + 3, (u32)(t + 1));       // xt_ready
    } else if (w == 0){
      spin_tok(ltok + 2, (u32)(t + 1));
      __builtin_amdgcn_sched_barrier(0);
      float hn0v[4], hn1v[4];
      #pragma unroll
      for (int j = 0; j < 4; ++j){
        int b = lk * 4 + j;
        float hn0 = tanh_fast(uc0[j] + a0[j] + xg[((par * 2 + 0) * 16 + b) * 16 + lr] * hp0[j]);
        float hn1 = tanh_fast(uc1[j] + a1[j] + xg[((par * 2 + 1) * 16 + b) * 16 + lr] * hp1[j]);
        hp0[j] = hn0; hp1[j] = hn1;
        hn0v[j] = hn0; hn1v[j] = hn1;
        u32 u0 = __float_as_uint(hn0), u1 = __float_as_uint(hn1);
        int bi = b * 512;
        st2<false>(wb + bi + ncol0,      u0 >> 16);
        st2<false>(wb + bi + ncol0 + 16, u1 >> 16);
        float lo0 = hn0 - __uint_as_float(u0 & 0xffff0000u);
        float lo1 = hn1 - __uint_as_float(u1 & 0xffff0000u);
        st2<false>(wb + 8192 + bi + ncol0,      __float_as_uint(lo0) >> 16);
        st2<false>(wb + 8192 + bi + ncol0 + 16, __float_as_uint(lo1) >> 16);
      }
      #pragma unroll
      for (int j = 0; j < 4; ++j){
        size_t ro = (size_t)(tn * 16 + lk * 4 + j) * 512;
        un0[j] = U1[ro + ncol0];
        un1[j] = U1[ro + ncol0 + 16];
      }
      asm volatile("s_waitcnt vmcnt(8)" ::: "memory");  // 16 state stores done
      if (l == 0)
        __hip_atomic_fetch_add(hcnt + (size_t)t * 32, 1u,
                               __ATOMIC_RELAXED, __HIP_MEMORY_SCOPE_WORKGROUP);
      #pragma unroll
      for (int j = 0; j < 4; ++j){
        int b = lk * 4 + j;
        size_t ob = (size_t)b * (SEQT * 512) + (size_t)t * 512;
        out[ob + ncol0]      = hn0v[j];
        out[ob + ncol0 + 16] = hn1v[j];
        if (t == SEQT - 1){
          out[8388608 + (size_t)b * 512 + ncol0]      = hn0v[j];
          out[8388608 + (size_t)b * 512 + ncol0 + 16] = hn1v[j];
        }
      }
    } else { // w == 2
      spin_tok(ltok + 3, (u32)(t + 1));
      __builtin_amdgcn_sched_barrier(0);
      float cn0v[4], cn1v[4];
      #pragma unroll
      for (int j = 0; j < 4; ++j){
        int b = lk * 4 + j;
        float cn0 = sigmoidf_(uc0[j] + a0[j]) * xt[((par * 2 + 0) * 16 + b) * 16 + lr];
        float cn1 = sigmoidf_(uc1[j] + a1[j]) * xt[((par * 2 + 1) * 16 + b) * 16 + lr];
        cn0v[j] = cn0; cn1v[j] = cn1;
        u32 u0 = __float_as_uint(cn0), u1 = __float_as_uint(cn1);
        int bi = b * 512;
        st2<false>(wb + 16384 + bi + ncol0,      u0 >> 16);
        st2<false>(wb + 16384 + bi + ncol0 + 16, u1 >> 16);
        float lo0 = cn0 - __uint_as_float(u0 & 0xffff0000u);
        float lo1 = cn1 - __uint_as_float(u1 & 0xffff0000u);
        st2<false>(wb + 24576 + bi + ncol0,      __float_as_uint(lo0) >> 16);
        st2<false>(wb + 24576 + bi + ncol0 + 16, __float_as_uint(lo1) >> 16);
      }
      #pragma unroll
      for (int j = 0; j < 4; ++j){
        size_t ro = (size_t)(tn * 16 + lk * 4 + j) * 512;
        ur0[j] = U2[ro + ncol0];
        ur1[j] = U2[ro + ncol0 + 16];
      }
      asm volatile("s_waitcnt vmcnt(8)" ::: "memory");
      if (l == 0)
        __hip_atomic_fetch_add(ccnt + (size_t)t * 32, 1u,
                               __ATOMIC_RELAXED, __HIP_MEMORY_SCOPE_WORKGROUP);
      if (t == SEQT - 1){
        #pragma unroll
        for (int j = 0; j < 4; ++j){
          int b = lk * 4 + j;
          out[8396800 + (size_t)b * 512 + ncol0]      = cn0v[j];
          out[8396800 + (size_t)b * 512 + ncol0 + 16] = cn1v[j];
        }
      }
    }
  }
}

// --- CC fallback scan (round-2/6-proven MALL path), used for modes 2/3 ---
__device__ __forceinline__ void scan_cc(
    int wg, int tid,
    const float* __restrict__ U1, const u16* __restrict__ U2,
    const u16* __restrict__ Wt, u16* __restrict__ st,
    u32* __restrict__ flags, float* __restrict__ out, float* xg, float* xt){
  const int w = tid >> 6, l = tid & 63;
  const int lr = l & 15, lk = l >> 4;
  const int ncol0 = wg * 32 + lr;
  s8v bf0[16], bf1[16];
  {
    const u16* Wm = Wt + (size_t)w * (512 * 512);
    #pragma unroll
    for (int ks = 0; ks < 16; ++ks){
      bf0[ks] = *(const s8v*)(Wm + (size_t)ncol0 * 512 + ks * 32 + lk * 8);
      bf1[ks] = *(const s8v*)(Wm + (size_t)(ncol0 + 16) * 512 + ks * 32 + lk * 8);
    }
  }
  const bool useH = (w == 0) || (w == 3);
  float hp0[4] = {0, 0, 0, 0}, hp1[4] = {0, 0, 0, 0};
  long guard = 0;
  for (int t = 0; t < SEQT; ++t){
    float uu0[4], uu1[4];
    if (w == 0){
      #pragma unroll
      for (int j = 0; j < 4; ++j){
        size_t ro = (size_t)(t * 16 + lk * 4 + j) * 512;
        uu0[j] = U1[ro + ncol0];
        uu1[j] = U1[ro + ncol0 + 16];
      }
    } else if (w == 2){
      #pragma unroll
      for (int j = 0; j < 4; ++j){
        size_t ro = (size_t)(t * 16 + lk * 4 + j) * 512;
        uu0[j] = bf2f(U2[ro + ncol0]);
        uu1[j] = bf2f(U2[ro + ncol0 + 16]);
      }
    }
    if (t > 0){
      const u32* fl = flags + (size_t)(t - 1) * NWG;
      for (;;){
        u32 v = 1u;
        if (l < NWG) v = __hip_atomic_load(fl + l, __ATOMIC_RELAXED, __HIP_MEMORY_SCOPE_AGENT);
        if (__all(v != 0u)) break;
        if (++guard > 1000000L) break;
      }
      __builtin_amdgcn_sched_barrier(0);
    }
    u16* rb = st + (size_t)(t & (PROT - 1)) * 32768 + (useH ? 0 : 16384);
    s8v ah[16], al[16];
    {
      u16* bhp = rb + lr * 512 + lk * 8;
      u16* blp = rb + 8192 + lr * 512 + lk * 8;
      #pragma unroll
      for (int ks = 0; ks < 16; ++ks){
        ah[ks] = ld16<true>(bhp + ks * 32);
        al[ks] = ld16<true>(blp + ks * 32);
      }
    }
    asm volatile("s_waitcnt vmcnt(0)" ::: "memory");
    __builtin_amdgcn_sched_barrier(0);
    f4v a0 = {0, 0, 0, 0}, a1 = {0, 0, 0, 0};
    f4v b0 = {0, 0, 0, 0}, b1 = {0, 0, 0, 0};
    #pragma unroll
    for (int ks = 0; ks < 16; ++ks){
      a0 = MFMA(ah[ks], bf0[ks], a0);
      a1 = MFMA(ah[ks], bf1[ks], a1);
      b0 = MFMA(al[ks], bf0[ks], b0);
      b1 = MFMA(al[ks], bf1[ks], b1);
    }
    #pragma unroll
    for (int j = 0; j < 4; ++j){ a0[j] += b0[j]; a1[j] += b1[j]; }
    if (w == 1){
      #pragma unroll
      for (int j = 0; j < 4; ++j){
        xg[(0 * 16 + lk * 4 + j) * 16 + lr] = sigmoidf_(a0[j]);
        xg[(1 * 16 + lk * 4 + j) * 16 + lr] = sigmoidf_(a1[j]);
      }
    } else if (w == 3){
      #pragma unroll
      for (int j = 0; j < 4; ++j){
        xt[(0 * 16 + lk * 4 + j) * 16 + lr] = tanh_fast(a0[j]);
        xt[(1 * 16 + lk * 4 + j) * 16 + lr] = tanh_fast(a1[j]);
      }
    }
    __syncthreads();
    u16* wb = st + (size_t)((t + 1) & (PROT - 1)) * 32768;
    float hn0v[4], hn1v[4], cn0v[4], cn1v[4];
    if (w == 0){
      #pragma unroll
      for (int j = 0; j < 4; ++j){
        int b = lk * 4 + j;
        float hn0 = tanh_fast(uu0[j] + a0[j] + xg[(0 * 16 + b) * 16 + lr] * hp0[j]);
        float hn1 = tanh_fast(uu1[j] + a1[j] + xg[(1 * 16 + b) * 16 + lr] * hp1[j]);
        hp0[j] = hn0; hp1[j] = hn1;
        hn0v[j] = hn0; hn1v[j] = hn1;
        u32 u0 = __float_as_uint(hn0), u1 = __float_as_uint(hn1);
        int bi = b * 512;
        st2<true>(wb + bi + ncol0,      u0 >> 16);
        st2<true>(wb + bi + ncol0 + 16, u1 >> 16);
        float lo0 = hn0 - __uint_as_float(u0 & 0xffff0000u);
        float lo1 = hn1 - __uint_as_float(u1 & 0xffff0000u);
        st2<true>(wb + 8192 + bi + ncol0,      __float_as_uint(lo0) >> 16);
        st2<true>(wb + 8192 + bi + ncol0 + 16, __float_as_uint(lo1) >> 16);
      }
      asm volatile("s_waitcnt vmcnt(0)" ::: "memory");
    } else if (w == 2){
      #pragma unroll
      for (int j = 0; j < 4; ++j){
        int b = lk * 4 + j;
        float cn0 = sigmoidf_(uu0[j] + a0[j]) * xt[(0 * 16 + b) * 16 + lr];
        float cn1 = sigmoidf_(uu1[j] + a1[j]) * xt[(1 * 16 + b) * 16 + lr];
        cn0v[j] = cn0; cn1v[j] = cn1;
        u32 u0 = __float_as_uint(cn0), u1 = __float_as_uint(cn1);
        int bi = b * 512;
        st2<true>(wb + 16384 + bi + ncol0,      u0 >> 16);
        st2<true>(wb + 16384 + bi + ncol0 + 16, u1 >> 16);
        float lo0 = cn0 - __uint_as_float(u0 & 0xffff0000u);
        float lo1 = cn1 - __uint_as_float(u1 & 0xffff0000u);
        st2<true>(wb + 24576 + bi + ncol0,      __float_as_uint(lo0) >> 16);
        st2<true>(wb + 24576 + bi + ncol0 + 16, __float_as_uint(lo1) >> 16);
      }
      asm volatile("s_waitcnt vmcnt(0)" ::: "memory");
    }
    __syncthreads();
    if (tid == 0) store_dword_cc(flags + (size_t)t * NWG + wg, 1u);
    if (w == 0){
      #pragma unroll
      for (int j = 0; j < 4; ++j){
        int b = lk * 4 + j;
        size_t ob = (size_t)b * (SEQT * 512) + (size_t)t * 512;
        out[ob + ncol0]      = hn0v[j];
        out[ob + ncol0 + 16] = hn1v[j];
        if (t == SEQT - 1){
          out[8388608 + (size_t)b * 512 + ncol0]      = hn0v[j];
          out[8388608 + (size_t)b * 512 + ncol0 + 16] = hn1v[j];
        }
      }
    } else if (w == 2 && t == SEQT - 1){
      #pragma unroll
      for (int j = 0; j < 4; ++j){
        int b = lk * 4 + j;
        out[8396800 + (size_t)b * 512 + ncol0]      = cn0v[j];
        out[8396800 + (size_t)b * 512 + ncol0 + 16] = cn1v[j];
      }
    }
  }
}

// --- persistent scan: election onto XCD0 + probe + heater + fallback ---
__global__ __launch_bounds__(256, 1) void recurk(
    const float* __restrict__ U1, const u16* __restrict__ U2,
    const u16* __restrict__ Wt, u16* __restrict__ st,
    u32* __restrict__ flags, u32* __restrict__ hcnt, u32* __restrict__ ccnt,
    u32* __restrict__ tok, u32* __restrict__ prs,
    u32* __restrict__ ctl, float* __restrict__ out){
  const int tid = threadIdx.x;
  __shared__ int slot_sh, mode_sh;
  __shared__ float xg[4 * 16 * 16], xt[4 * 16 * 16];
  __shared__ u32 ltok[4];
  u32* cntp  = ctl;
  u32* modep = ctl + 16;
  u32* donep = ctl + 64;

  if (tid == 0){
    int s = -1;
    u32 xcc;
    asm volatile("s_getreg_b32 %0, hwreg(HW_REG_XCC_ID)" : "=s"(xcc));
    if ((xcc & 0xfu) == 0u)
      s = (int)__hip_atomic_fetch_add(cntp, 1u, __ATOMIC_RELAXED,
                                      __HIP_MEMORY_SCOPE_AGENT);
    slot_sh = s;
  }
  __syncthreads();
  const int slot = slot_sh;

  if (tid == 0){
    if (slot >= 0 && slot < NWG){
      store_dword_plain_wait(tok + slot * 16, 0x5A5A0000u + (u32)slot);
      __hip_atomic_store(prs + slot * 16, 1u, __ATOMIC_RELAXED,
                         __HIP_MEMORY_SCOPE_AGENT);
    }
    if (blockIdx.x == 0){
      long g = 0;
      for (;;){
        u32 c = __hip_atomic_load(cntp, __ATOMIC_RELAXED, __HIP_MEMORY_SCOPE_AGENT);
        if (c >= NWG) break;
        if (++g > 2000000L){ atomicCAS(modep, 0u, 2u); break; }
      }
    }
    if (slot == 0){
      bool ok = true;
      long g = 0;
      for (int s2 = 1; s2 < NWG && ok; ++s2){
        for (;;){
          u32 p = __hip_atomic_load(prs + s2 * 16, __ATOMIC_RELAXED,
                                    __HIP_MEMORY_SCOPE_AGENT);
          if (p) break;
          if (++g > 5000000L){ ok = false; break; }
        }
      }
      if (ok){
        for (int s2 = 1; s2 < NWG; ++s2){
          u32 v = load_dword_plain_wait(tok + s2 * 16);
          if (v != 0x5A5A0000u + (u32)s2){ ok = false; break; }
        }
      }
      atomicCAS(modep, 0u, ok ? 1u : 3u);
    }
    long g = 0;
    u32 m;
    for (;;){
      m = __hip_atomic_load(modep, __ATOMIC_RELAXED, __HIP_MEMORY_SCOPE_AGENT);
      if (m) break;
      if (++g > 50000000L){ m = 3u; break; }
    }
    mode_sh = (int)m;
  }
  if (tid < 4) ltok[tid] = 0;
  __syncthreads();
  const int mode = mode_sh;

  int wg; bool part;
  if (mode == 2){ wg = blockIdx.x; part = (wg < NWG); }
  else          { wg = slot;       part = (slot >= 0 && slot < NWG); }

  if (!part){
    heater(donep);                 // keep clocks boosted while scan runs
    return;
  }

  if (mode == 1) scan_fast(wg, tid, U1, U2, Wt, st, hcnt, ccnt, out, xg, xt, ltok);
  else           scan_cc (wg, tid, U1, U2, Wt, st, flags, out, xg, xt);

  if (wg == 0 && tid == 0)
    __hip_atomic_store(donep, 1u, __ATOMIC_RELAXED, __HIP_MEMORY_SCOPE_AGENT);
}

extern "C" void kernel_launch(void* const* d_in, const int* in_sizes, int n_in,
                              void* d_out, int out_size, void* d_ws, size_t ws_size,
                              hipStream_t stream){
  const float* x   = (const float*)d_in[0];
  const float* Wfc = (const float*)d_in[1];
  const float* bfc = (const float*)d_in[2];
  const float* W1x = (const float*)d_in[3];
  const float* W1h = (const float*)d_in[4];
  const float* W1g = (const float*)d_in[5];
  const float* W2x = (const float*)d_in[6];
  const float* W2h = (const float*)d_in[7];
  const float* W2g = (const float*)d_in[8];

  char* ws = (char*)d_ws;
  float* U1   = (float*)(ws + OFF_U1);
  u16*   U2   = (u16*)  (ws + OFF_U2);
  u16*   Wct  = (u16*)  (ws + OFF_WCT);
  u16*   st   = (u16*)  (ws + OFF_ST);     // aliases Wct (dead after gemmk)
  u16*   Wt   = (u16*)  (ws + OFF_WT);
  float* bc   = (float*)(ws + OFF_BC);
  u32*   flags= (u32*)  (ws + OFF_FL);
  u32*   tok  = (u32*)  (ws + OFF_TOK);
  u32*   prs  = (u32*)  (ws + OFF_PRS);
  u32*   ctl  = (u32*)  (ws + OFF_CTL);
  u32*   hcnt = (u32*)  (ws + OFF_HCN);
  u32*   ccnt = (u32*)  (ws + OFF_CCN);
  float* out  = (float*)d_out;

  // zero CC flags + tokens + present + control(+done) every launch
  hipMemsetAsync(ws + OFF_FL, 0, 65536 + 4096 + 4096 + 4096 + 4096, stream);
  // zero padded step counters (h + c, 256 KB)
  hipMemsetAsync(ws + OFF_HCN, 0, 262144, stream);

  wcombk<<<dim3(32, 32, 2), dim3(16, 16), 0, stream>>>(Wfc, W1x, W2x, Wct);
  bcombk<<<dim3(4), dim3(256), 0, stream>>>(bfc, W1x, W2x, bc);
  wtk   <<<dim3(16, 16, 4), dim3(32, 8), 0, stream>>>(W1h, W1g, W2h, W2g, Wt);
  gemmk <<<dim3(16, 128), dim3(256), 0, stream>>>(x, Wct, bc, U1, U2);
  // Wct is dead now; zero the aliased state-rotation region (slot 0 = h0,c0)
  hipMemsetAsync(ws + OFF_ST, 0, 1048576, stream);
  recurk<<<dim3(256), dim3(256), 0, stream>>>(U1, U2, Wt, st, flags, hcnt, ccnt, tok, prs, ctl, out);
}